// Round 20
// baseline (1537.073 us; speedup 1.0000x reference)
//
#include <hip/hip_runtime.h>
#include <math.h>

#define NCHUNK 32
typedef unsigned long long ull;

__device__ __forceinline__ float gelu_f(float v){
  return 0.5f*v*(1.0f+erff(v*0.70710678118654752440f));
}

__device__ __forceinline__ unsigned flipf(float d){
  unsigned u = __float_as_uint(d);
  return (u & 0x80000000u) ? ~u : (u | 0x80000000u);
}

// ---- DPP helpers ----
template<int CTRL>
__device__ __forceinline__ ull dpp64(ull k){
  int lo = __builtin_amdgcn_update_dpp(0, (int)(unsigned)k,       CTRL, 0xF, 0xF, true);
  int hi = __builtin_amdgcn_update_dpp(0, (int)(unsigned)(k>>32), CTRL, 0xF, 0xF, true);
  return ((ull)(unsigned)hi<<32) | (unsigned)lo;
}
__device__ __forceinline__ ull rl64(ull k, int l){
  unsigned lo = (unsigned)__builtin_amdgcn_readlane((int)(unsigned)k, l);
  unsigned hi = (unsigned)__builtin_amdgcn_readlane((int)(unsigned)(k>>32), l);
  return ((ull)hi<<32) | lo;
}
// FPS keys: hi = float bits of nd>=0 -> u64 order == f64 order (positive doubles).
__device__ __forceinline__ ull fmax64(ull a, ull b){
  return (ull)__double_as_longlong(fmax(__longlong_as_double((long long)a),
                                        __longlong_as_double((long long)b)));
}
__device__ __forceinline__ ull wave_fmax(ull k){
  k = fmax64(k, dpp64<0xB1>(k));
  k = fmax64(k, dpp64<0x4E>(k));
  k = fmax64(k, dpp64<0x141>(k));
  k = fmax64(k, dpp64<0x140>(k));
  ull a=rl64(k,0), b=rl64(k,16), c=rl64(k,32), d=rl64(k,48);
  return fmax64(fmax64(a,b), fmax64(c,d));
}
// kNN keys are positive doubles (flip*4096+j) -> f64 min directly.
template<int CTRL>
__device__ __forceinline__ double dmin_dpp(double k){
  ull o = dpp64<CTRL>((ull)__double_as_longlong(k));
  return fmin(k, __longlong_as_double((long long)o));
}
__device__ __forceinline__ double wave_dmin(double k){
  k = dmin_dpp<0xB1>(k);
  k = dmin_dpp<0x4E>(k);
  k = dmin_dpp<0x141>(k);
  k = dmin_dpp<0x140>(k);
  ull kb = (ull)__double_as_longlong(k);
  double a = __longlong_as_double((long long)rl64(kb,0));
  double b = __longlong_as_double((long long)rl64(kb,16));
  double c = __longlong_as_double((long long)rl64(kb,32));
  double d = __longlong_as_double((long long)rl64(kb,48));
  return fmin(fmin(a,b), fmin(c,d));
}

// ================= device bodies =================

// ---- wave-per-query kNN; key = flip(d)*4096 + j (exact f64, lex order) ----
template<int K, int T>
__device__ __forceinline__ void knn_body(
    const float* __restrict__ cand, int n,
    const float* __restrict__ qsrc, const int* __restrict__ qidx, int m,
    int* __restrict__ nbr, float* __restrict__ outc,
    int b, int qblk, int qoff, char* smem)
{
  float4* tile = (float4*)smem;   // 1024 entries, 16KB
  constexpr int NWV = T/64;
  int wv = threadIdx.x >> 6, lane = threadIdx.x & 63;
  int q = qblk*NWV + wv + qoff;
  const float* cb = cand + (size_t)b*3*n;
  int qi = qidx ? qidx[(size_t)b*m + q] : q;
  const float* qb = qsrc + (size_t)b*3*n;
  float qx = qb[qi], qy = qb[n+qi], qz = qb[2*n+qi];
  float aa = (qx*qx + qy*qy) + qz*qz;

  double a[K];
  #pragma unroll
  for (int k=0;k<K;k++) a[k] = 1e300;

  for (int base=0; base<n; base+=1024){
    int cnt = min(1024, n-base);
    for (int j=threadIdx.x; j<cnt; j+=T){
      float x=cb[base+j], y=cb[n+base+j], z=cb[2*n+base+j];
      tile[j] = make_float4(x,y,z,(x*x+y*y)+z*z);
    }
    __syncthreads();
    int steps = cnt >> 6;
    double jd = (double)(base + lane);
    for (int i=0;i<steps;i++){
      int j = lane + (i<<6);
      float4 c = tile[j];
      float d = aa + c.w - 2.0f*((qx*c.x+qy*c.y)+qz*c.z);
      double key = (double)flipf(d) * 4096.0 + jd;
      if (key < a[K-1]){
        #pragma unroll
        for (int k=K-1;k>=1;k--)
          a[k] = fmin(fmax(a[k-1], key), a[k]);
        a[0] = fmin(a[0], key);
      }
      jd += 64.0;
    }
    __syncthreads();
  }

  double head = a[0];
  int res[K];
  #pragma unroll
  for (int r=0; r<K; r++){
    double mk = wave_dmin(head);
    res[r] = (int)((ull)mk & 4095u);
    if (head == mk){
      #pragma unroll
      for (int i2=0;i2<K-1;i2++) a[i2]=a[i2+1];
      a[K-1] = 1e300;
      head = a[0];
    }
  }
  if (lane == 0){
    int* o = nbr + ((size_t)b*m + q)*K;
    #pragma unroll
    for (int r=0;r<K;r++) o[r] = res[r];
  }
  if (outc != nullptr && lane < 3){
    const float* cd = cb + (size_t)lane*n;
    float s=0;
    #pragma unroll
    for (int k=0;k<K;k++) s += cd[res[k]];
    outc[((size_t)b*3 + lane)*m + q] = s * (1.0f/K);
  }
}

// ---- top-K from Gram rows (f64 keys) body ----
template<int K>
__device__ __forceinline__ void topk_body(
    const float* __restrict__ G, const float* __restrict__ aa, int m,
    int* __restrict__ nbr, int b, int qblk, char* smem)
{
  float* abs_s = (float*)smem;
  int wv = threadIdx.x >> 6, lane = threadIdx.x & 63;
  int q = qblk*4 + wv;
  const float* ab = aa + (size_t)b*m;
  for (int j=threadIdx.x; j<m; j+=256) abs_s[j] = ab[j];
  __syncthreads();
  float aq = ab[q];
  const float* Gq = G + ((size_t)b*m + q)*m;

  double a[K];
  #pragma unroll
  for (int k=0;k<K;k++) a[k] = 1e300;

  int steps = (m+63)>>6;
  double jd = (double)lane;
  for (int i=0;i<steps;i++){
    int j = lane + (i<<6);
    double key = 1e300;
    if (j < m){
      float g = Gq[j];
      float d = aq + abs_s[j] - 2.0f*g;
      key = (double)flipf(d) * 4096.0 + jd;
    }
    if (key < a[K-1]){
      #pragma unroll
      for (int k=K-1;k>=1;k--)
        a[k] = fmin(fmax(a[k-1], key), a[k]);
      a[0] = fmin(a[0], key);
    }
    jd += 64.0;
  }
  double head = a[0];
  int res[K];
  #pragma unroll
  for (int r=0; r<K; r++){
    double mk = wave_dmin(head);
    res[r] = (int)((ull)mk & 4095u);
    if (head == mk){
      #pragma unroll
      for (int i2=0;i2<K-1;i2++) a[i2]=a[i2+1];
      a[K-1] = 1e300;
      head = a[0];
    }
  }
  if (lane == 0){
    int* o = nbr + ((size_t)b*m + q)*K;
    #pragma unroll
    for (int r=0;r<K;r++) o[r] = res[r];
  }
}

// ---- segmented multi-wave FPS (stage 0) ----
template<int NP, int T, int M>
__device__ __forceinline__ void fps_mw_seg(const float* __restrict__ cur, int n,
                                           int* __restrict__ sind, float* __restrict__ gdmin,
                                           int b, int M0, int M1, char* smem)
{
  constexpr int NW = T/64;
  int tid = threadIdx.x;
  int wv = tid>>6;
  const float* cb = cur + (size_t)b*3*n;
  float4* lp = (float4*)smem;
  ull* wred = (ull*)(smem + sizeof(float4)*NP*T);
  float* gd = gdmin + (size_t)b*n;
  float px[NP], py[NP], pz[NP], dmin[NP];
  unsigned nj[NP];
  #pragma unroll
  for (int s=0;s<NP;s++){
    int j = tid + s*T;
    px[s]=cb[j]; py[s]=cb[n+j]; pz[s]=cb[2*n+j];
    dmin[s] = (M0==0) ? 1e30f : gd[j];
    nj[s] = (unsigned)(~j);
    lp[j] = make_float4(px[s],py[s],pz[s],0.f);
  }
  __syncthreads();
  int ci = (M0==0) ? 0 : sind[(size_t)b*M + (M0-1)];
  float4 w0 = lp[ci];
  float X = w0.x, Y = w0.y, Z = w0.z;
  if (M0==0 && tid==0) sind[(size_t)b*M] = 0;
  __builtin_amdgcn_s_setprio(3);
  int p = 0;
  int s0 = (M0==0) ? 1 : M0;
  for (int step=s0; step<M1; step++){
    ull key[NP];
    #pragma unroll
    for (int s=0;s<NP;s++){
      float dx=px[s]-X, dy=py[s]-Y, dz=pz[s]-Z;
      float d = (dx*dx + dy*dy) + dz*dz;
      float nd = fminf(dmin[s], d);
      dmin[s] = nd;
      key[s] = ((ull)__float_as_uint(nd)<<32) | nj[s];
    }
    #pragma unroll
    for (int w=NP; w>1; w>>=1)
      #pragma unroll
      for (int i=0;i<NP;i++) if (i < (w>>1))
        key[i] = fmax64(key[i], key[i+(w>>1)]);
    ull wk = wave_fmax(key[0]);
    if ((tid&63)==0) wred[p*NW + wv] = wk;
    __syncthreads();
    const ulonglong2* wp2 = (const ulonglong2*)(wred + p*NW);
    ulonglong2 m0 = wp2[0], m1 = wp2[1], m2 = wp2[2], m3 = wp2[3];
    ull gk = fmax64(fmax64(fmax64(m0.x,m0.y), fmax64(m1.x,m1.y)),
                    fmax64(fmax64(m2.x,m2.y), fmax64(m3.x,m3.y)));
    int gi = (int)(~(unsigned)gk);
    if (tid==0) sind[(size_t)b*M + step] = gi;
    float4 wp = lp[gi];
    X=wp.x; Y=wp.y; Z=wp.z;
    p ^= 1;
  }
  __builtin_amdgcn_s_setprio(0);
  #pragma unroll
  for (int s=0;s<NP;s++) gd[tid + s*T] = dmin[s];
}

// ---- single-wave FPS (non-segmented) ----
template<int NP, int M>
__device__ __forceinline__ void fps_sw_body(const float* __restrict__ cur, int n,
                                            int* __restrict__ sind, int b, char* smem)
{
  int lane = threadIdx.x;
  const float* cb = cur + (size_t)b*3*n;
  float4* lp = (float4*)smem;
  float px[NP], py[NP], pz[NP], dmin[NP];
  unsigned nj[NP];
  #pragma unroll
  for (int s=0;s<NP;s++){
    int j = lane + s*64;
    px[s]=cb[j]; py[s]=cb[n+j]; pz[s]=cb[2*n+j]; dmin[s]=1e30f;
    nj[s] = (unsigned)(~j);
    lp[j] = make_float4(px[s],py[s],pz[s],0.f);
  }
  float X = lp[0].x, Y = lp[0].y, Z = lp[0].z;
  if (lane==0) sind[(size_t)b*M] = 0;
  __builtin_amdgcn_s_setprio(3);
  for (int step=1; step<M; step++){
    ull key[NP];
    #pragma unroll
    for (int s=0;s<NP;s++){
      float dx=px[s]-X, dy=py[s]-Y, dz=pz[s]-Z;
      float d = (dx*dx + dy*dy) + dz*dz;
      float nd = fminf(dmin[s], d);
      dmin[s] = nd;
      key[s] = ((ull)__float_as_uint(nd)<<32) | nj[s];
    }
    #pragma unroll
    for (int w=NP; w>1; w>>=1)
      #pragma unroll
      for (int i=0;i<NP;i++) if (i < (w>>1))
        key[i] = fmax64(key[i], key[i+(w>>1)]);
    ull gk = wave_fmax(key[0]);
    int gi = (int)(~(unsigned)gk);
    if (lane==0) sind[(size_t)b*M + step] = gi;
    float4 wp = lp[gi];
    X=wp.x; Y=wp.y; Z=wp.z;
  }
  __builtin_amdgcn_s_setprio(0);
}

// ---- single-wave FPS, segmented ----
template<int NP, int M>
__device__ __forceinline__ void fps_sw_seg(const float* __restrict__ cur, int n,
                                           int* __restrict__ sind, float* __restrict__ gdmin,
                                           int b, int M0, int M1, char* smem)
{
  int lane = threadIdx.x;
  const float* cb = cur + (size_t)b*3*n;
  float4* lp = (float4*)smem;
  float* gd = gdmin + (size_t)b*n;
  float px[NP], py[NP], pz[NP], dmin[NP];
  unsigned nj[NP];
  #pragma unroll
  for (int s=0;s<NP;s++){
    int j = lane + s*64;
    px[s]=cb[j]; py[s]=cb[n+j]; pz[s]=cb[2*n+j];
    dmin[s] = (M0==0) ? 1e30f : gd[j];
    nj[s] = (unsigned)(~j);
    lp[j] = make_float4(px[s],py[s],pz[s],0.f);
  }
  int ci = (M0==0) ? 0 : sind[(size_t)b*M + (M0-1)];
  float4 w0 = lp[ci];
  float X = w0.x, Y = w0.y, Z = w0.z;
  if (M0==0 && lane==0) sind[(size_t)b*M] = 0;
  __builtin_amdgcn_s_setprio(3);
  int s0 = (M0==0) ? 1 : M0;
  for (int step=s0; step<M1; step++){
    ull key[NP];
    #pragma unroll
    for (int s=0;s<NP;s++){
      float dx=px[s]-X, dy=py[s]-Y, dz=pz[s]-Z;
      float d = (dx*dx + dy*dy) + dz*dz;
      float nd = fminf(dmin[s], d);
      dmin[s] = nd;
      key[s] = ((ull)__float_as_uint(nd)<<32) | nj[s];
    }
    #pragma unroll
    for (int w=NP; w>1; w>>=1)
      #pragma unroll
      for (int i=0;i<NP;i++) if (i < (w>>1))
        key[i] = fmax64(key[i], key[i+(w>>1)]);
    ull gk = wave_fmax(key[0]);
    int gi = (int)(~(unsigned)gk);
    if (lane==0) sind[(size_t)b*M + step] = gi;
    float4 wp = lp[gi];
    X=wp.x; Y=wp.y; Z=wp.z;
  }
  __builtin_amdgcn_s_setprio(0);
  #pragma unroll
  for (int s=0;s<NP;s++) gd[lane + s*64] = dmin[s];
}

// ---- tiled NT GEMM body; BN variant finalizes mu/var from `part` in LDS ----
template<bool DUAL, bool BN>
__device__ __forceinline__ void gemm_body(
    const float* __restrict__ A, const float* __restrict__ B,
    float* __restrict__ out0, float* __restrict__ out1,
    int M, int N, int Kd, int lda, int ldb, int ldo, int boff,
    long sA, long sB, long sO, const float* __restrict__ part, float invR,
    int bxi, int byi, int bzi, char* smem)
{
  A += (size_t)bzi * sA; B += (size_t)bzi * sB;
  float* o0 = out0 + (size_t)bzi * sO;
  float* o1 = DUAL ? (out1 + (size_t)bzi * sO) : nullptr;
  int rowBase = byi*64, colBase = bxi*64;
  float (*As)[64]  = (float(*)[64])smem;
  float (*Bs0)[64] = (float(*)[64])(smem + 4096);
  float (*Bs1)[64] = (float(*)[64])(smem + 8192);
  float* mu_s = (float*)(smem + 12288);
  float* var_s = mu_s + 512;
  int tid = threadIdx.x;
  if (BN){
    for (int oo=tid; oo<Kd; oo+=blockDim.x){
      float s=0, q=0;
      #pragma unroll 4
      for (int c=0;c<NCHUNK;c++){
        s += part[(size_t)c*1024 + oo];
        q += part[(size_t)(NCHUNK+c)*1024 + oo];
      }
      float mu = s*invR;
      mu_s[oo] = mu;
      var_s[oo] = q*invR - mu*mu;
    }
    __syncthreads();
  }
  int ty = tid>>4, tx = tid&15;
  float acc0[4][4] = {}, acc1[4][4] = {};
  int lr = tid>>2, lk = (tid&3)*4;
  for (int k0=0; k0<Kd; k0+=16) {
    float4 va = make_float4(0,0,0,0);
    int r = rowBase + lr;
    if (r < M) va = *(const float4*)(A + (size_t)r*lda + k0 + lk);
    if (BN){
      int c = k0 + lk;
      va.x = gelu_f((va.x - mu_s[c+0]) / sqrtf(var_s[c+0] + 1e-5f));
      va.y = gelu_f((va.y - mu_s[c+1]) / sqrtf(var_s[c+1] + 1e-5f));
      va.z = gelu_f((va.z - mu_s[c+2]) / sqrtf(var_s[c+2] + 1e-5f));
      va.w = gelu_f((va.w - mu_s[c+3]) / sqrtf(var_s[c+3] + 1e-5f));
    }
    As[lk+0][lr]=va.x; As[lk+1][lr]=va.y; As[lk+2][lr]=va.z; As[lk+3][lr]=va.w;
    float4 vb = make_float4(0,0,0,0), vb2 = make_float4(0,0,0,0);
    int c2 = colBase + lr;
    if (c2 < N) {
      vb = *(const float4*)(B + (size_t)c2*ldb + k0 + lk);
      if (DUAL) vb2 = *(const float4*)(B + (size_t)c2*ldb + boff + k0 + lk);
    }
    Bs0[lk+0][lr]=vb.x; Bs0[lk+1][lr]=vb.y; Bs0[lk+2][lr]=vb.z; Bs0[lk+3][lr]=vb.w;
    if (DUAL) {
      Bs1[lk+0][lr]=vb2.x-vb.x; Bs1[lk+1][lr]=vb2.y-vb.y;
      Bs1[lk+2][lr]=vb2.z-vb.z; Bs1[lk+3][lr]=vb2.w-vb.w;
    }
    __syncthreads();
    #pragma unroll
    for (int kk=0;kk<16;kk++){
      float4 a  = *(const float4*)&As[kk][ty*4];
      float4 b0 = *(const float4*)&Bs0[kk][tx*4];
      float av[4]={a.x,a.y,a.z,a.w};
      float b0v[4]={b0.x,b0.y,b0.z,b0.w};
      #pragma unroll
      for (int i=0;i<4;i++)
        #pragma unroll
        for (int j=0;j<4;j++) acc0[i][j] = fmaf(av[i], b0v[j], acc0[i][j]);
      if (DUAL) {
        float4 b1 = *(const float4*)&Bs1[kk][tx*4];
        float b1v[4]={b1.x,b1.y,b1.z,b1.w};
        #pragma unroll
        for (int i=0;i<4;i++)
          #pragma unroll
          for (int j=0;j<4;j++) acc1[i][j] = fmaf(av[i], b1v[j], acc1[i][j]);
      }
    }
    __syncthreads();
  }
  #pragma unroll
  for (int i=0;i<4;i++){
    int r = rowBase + ty*4 + i;
    if (r < M) {
      #pragma unroll
      for (int j=0;j<4;j++){
        int c = colBase + tx*4 + j;
        if (c < N) {
          o0[(size_t)r*ldo + c] = acc0[i][j];
          if (DUAL) o1[(size_t)r*ldo + c] = acc1[i][j];
        }
      }
    }
  }
}

// ---- guarded GEMM body for 512-thread co-launch ----
template<bool DUAL, bool BN>
__device__ __forceinline__ void gemm_body_g(
    const float* __restrict__ A, const float* __restrict__ B,
    float* __restrict__ out0, float* __restrict__ out1,
    int M, int N, int Kd, int lda, int ldb, int ldo, int boff,
    const float* __restrict__ part, float invR,
    int bxi, int byi, char* smem)
{
  int rowBase = byi*64, colBase = bxi*64;
  float (*As)[64]  = (float(*)[64])smem;
  float (*Bs0)[64] = (float(*)[64])(smem + 4096);
  float (*Bs1)[64] = (float(*)[64])(smem + 8192);
  float* mu_s = (float*)(smem + 12288);
  float* var_s = mu_s + 512;
  int tid = threadIdx.x;
  bool act = tid < 256;
  if (BN){
    for (int oo=tid; oo<Kd; oo+=blockDim.x){
      float s=0, q=0;
      #pragma unroll 4
      for (int c=0;c<NCHUNK;c++){
        s += part[(size_t)c*1024 + oo];
        q += part[(size_t)(NCHUNK+c)*1024 + oo];
      }
      float mu = s*invR;
      mu_s[oo] = mu;
      var_s[oo] = q*invR - mu*mu;
    }
    __syncthreads();
  }
  int ty = tid>>4, tx = tid&15;
  float acc0[4][4] = {}, acc1[4][4] = {};
  int lr = tid>>2, lk = (tid&3)*4;
  for (int k0=0; k0<Kd; k0+=16) {
    if (act){
      float4 va = make_float4(0,0,0,0);
      int r = rowBase + lr;
      if (r < M) va = *(const float4*)(A + (size_t)r*lda + k0 + lk);
      if (BN){
        int c = k0 + lk;
        va.x = gelu_f((va.x - mu_s[c+0]) / sqrtf(var_s[c+0] + 1e-5f));
        va.y = gelu_f((va.y - mu_s[c+1]) / sqrtf(var_s[c+1] + 1e-5f));
        va.z = gelu_f((va.z - mu_s[c+2]) / sqrtf(var_s[c+2] + 1e-5f));
        va.w = gelu_f((va.w - mu_s[c+3]) / sqrtf(var_s[c+3] + 1e-5f));
      }
      As[lk+0][lr]=va.x; As[lk+1][lr]=va.y; As[lk+2][lr]=va.z; As[lk+3][lr]=va.w;
      float4 vb = make_float4(0,0,0,0), vb2 = make_float4(0,0,0,0);
      int c2 = colBase + lr;
      if (c2 < N) {
        vb = *(const float4*)(B + (size_t)c2*ldb + k0 + lk);
        if (DUAL) vb2 = *(const float4*)(B + (size_t)c2*ldb + boff + k0 + lk);
      }
      Bs0[lk+0][lr]=vb.x; Bs0[lk+1][lr]=vb.y; Bs0[lk+2][lr]=vb.z; Bs0[lk+3][lr]=vb.w;
      if (DUAL) {
        Bs1[lk+0][lr]=vb2.x-vb.x; Bs1[lk+1][lr]=vb2.y-vb.y;
        Bs1[lk+2][lr]=vb2.z-vb.z; Bs1[lk+3][lr]=vb2.w-vb.w;
      }
    }
    __syncthreads();
    if (act){
      #pragma unroll
      for (int kk=0;kk<16;kk++){
        float4 a  = *(const float4*)&As[kk][ty*4];
        float4 b0 = *(const float4*)&Bs0[kk][tx*4];
        float av[4]={a.x,a.y,a.z,a.w};
        float b0v[4]={b0.x,b0.y,b0.z,b0.w};
        #pragma unroll
        for (int i=0;i<4;i++)
          #pragma unroll
          for (int j=0;j<4;j++) acc0[i][j] = fmaf(av[i], b0v[j], acc0[i][j]);
        if (DUAL) {
          float4 b1 = *(const float4*)&Bs1[kk][tx*4];
          float b1v[4]={b1.x,b1.y,b1.z,b1.w};
          #pragma unroll
          for (int i=0;i<4;i++)
            #pragma unroll
            for (int j=0;j<4;j++) acc1[i][j] = fmaf(av[i], b1v[j], acc1[i][j]);
        }
      }
    }
    __syncthreads();
  }
  if (act){
    #pragma unroll
    for (int i=0;i<4;i++){
      int r = rowBase + ty*4 + i;
      if (r < M) {
        #pragma unroll
        for (int j=0;j<4;j++){
          int c = colBase + tx*4 + j;
          if (c < N) {
            out0[(size_t)r*ldo + c] = acc0[i][j];
            if (DUAL) out1[(size_t)r*ldo + c] = acc1[i][j];
          }
        }
      }
    }
  }
}

// ---- plain gather + max ----
__device__ __forceinline__ void gather_elem(
    const float* __restrict__ P, const int* __restrict__ nbr,
    const float* __restrict__ addA, const float* __restrict__ addB,
    float* __restrict__ out, int n_out, int n_src, int O, int K, int total, int e)
{
  if (e >= total) return;
  int o = e % O; int r = e / O;
  int b = r / n_out; int i = r % n_out;
  const int* nb = nbr + ((size_t)b*n_out + i)*K;
  float mx = -1e38f;
  for (int k=0;k<K;k++){
    int j = nb[k];
    float v = P[((size_t)b*n_src + j)*O + o];
    mx = fmaxf(mx, v);
  }
  float res = mx;
  if (addA) res += addA[e];
  if (addB) res = addB[e] + res;
  out[e] = res;
}

// ---- downsample gather with BN+gelu on load + row-norm emit ----
__device__ __forceinline__ void gatherbn_body(
    const float* __restrict__ P, const int* __restrict__ nbr,
    const float* __restrict__ part, float invR,
    float* __restrict__ out, float* __restrict__ aa,
    int n_out, int n_src, int O, int K, int blk, char* smem)
{
  float* mu_s = (float*)smem; float* var_s = mu_s + 256; float* sv = var_s + 256;
  int tid = threadIdx.x;
  for (int oo=tid; oo<O; oo+=256){
    float s=0, q=0;
    #pragma unroll 4
    for (int c=0;c<NCHUNK;c++){
      s += part[(size_t)c*1024 + oo];
      q += part[(size_t)(NCHUNK+c)*1024 + oo];
    }
    float mu = s*invR;
    mu_s[oo] = mu;
    var_s[oo] = q*invR - mu*mu;
  }
  __syncthreads();
  int e = blk*256 + tid;
  int o = e % O; int r = e / O;
  int b = r / n_out; int i = r % n_out;
  const int* nb = nbr + ((size_t)b*n_out + i)*K;
  float mu = mu_s[o], sd = sqrtf(var_s[o] + 1e-5f);
  float mx = -1e38f;
  for (int k=0;k<K;k++){
    int j = nb[k];
    float p = P[((size_t)b*n_src + j)*O + o];
    float v = gelu_f((p - mu)/sd);
    mx = fmaxf(mx, v);
  }
  out[e] = mx;
  sv[tid] = mx*mx;
  __syncthreads();
  for (int st=O>>1; st>0; st>>=1){
    if (o < st) sv[tid] += sv[tid+st];
    __syncthreads();
  }
  if (o == 0) aa[r] = sv[tid];
}

// ================= global kernels =================

#define FPS_SMEM 65664   // 16*8*512 (float4 lp) + 2*8*8 (wred)

// mega1: [fps0 seg (0-3) | knn16 (4..2051) | mlp (2052..4099)] @512thr
__global__ __launch_bounds__(512,2) void mega1(
    const float* __restrict__ xyz, const float* __restrict__ x,
    const float* __restrict__ mlpw, const float* __restrict__ mlpb,
    int* __restrict__ sind0, float* __restrict__ gdmin,
    int* __restrict__ nbr0, float* __restrict__ hA, int M0, int M1)
{
  __shared__ __align__(16) char SMEM[FPS_SMEM];
  int bid = blockIdx.x;
  if (bid < 4){
    fps_mw_seg<8,512,1024>(xyz, 4096, sind0, gdmin, bid, M0, M1, SMEM);
  } else if (bid < 4+2048){
    int kb = bid - 4;
    knn_body<16,512>(xyz, 4096, xyz, nullptr, 4096, nbr0, nullptr, kb>>9, kb&511, 0, SMEM);
  } else {
    int e = (bid - 2052)*512 + threadIdx.x;
    if (e < 4*4096*64){
      int o = e & 63; int r = e >> 6;
      int b = r / 4096; int i = r % 4096;
      const float* xb = x + (size_t)b*3*4096;
      hA[e] = ((mlpw[o*3+0]*xb[i] + mlpw[o*3+1]*xb[4096+i]) + mlpw[o*3+2]*xb[2*4096+i]) + mlpb[o];
    }
  }
}

// [fps0 seg | bngelu-from-part] @512
__global__ __launch_bounds__(512,2) void fps_bngelu(
    const float* fcur, int* sind, float* gdmin, int M0, int M1,
    float* __restrict__ xx, const float* __restrict__ part, float invR, int O, int total)
{
  __shared__ __align__(16) char SMEM[FPS_SMEM];
  if (blockIdx.x < 4){
    fps_mw_seg<8,512,1024>(fcur, 4096, sind, gdmin, blockIdx.x, M0, M1, SMEM);
    return;
  }
  float* mu_s = (float*)SMEM; float* var_s = mu_s + 512;
  for (int oo=threadIdx.x; oo<O; oo+=512){
    float s=0, q=0;
    #pragma unroll 4
    for (int c=0;c<NCHUNK;c++){
      s += part[(size_t)c*1024 + oo];
      q += part[(size_t)(NCHUNK+c)*1024 + oo];
    }
    float mu = s*invR;
    mu_s[oo] = mu;
    var_s[oo] = q*invR - mu*mu;
  }
  __syncthreads();
  int e = (blockIdx.x-4)*512 + threadIdx.x;
  if (e >= total) return;
  int o = e % O;
  float v = (xx[e]-mu_s[o]) / sqrtf(var_s[o] + 1e-5f);
  xx[e] = gelu_f(v);
}

// [fps0 seg | knn8 slice | gemm] @512
template<bool DUAL, bool BN>
__global__ __launch_bounds__(512,2) void fps0_gemm_knn(
    const float* fcur, int* sind, float* gdmin, int M0, int M1,
    const float* cand, int n, const float* qsrc, const int* qidx, int m,
    int* nbrOut, float* outc, int qoff, int NQB, int KNB,
    const float* A, const float* B, float* out0, float* out1,
    int Mg, int Ng, int Kd, int lda, int ldb, int ldo, int boff,
    const float* part, float invR, int nbx)
{
  __shared__ __align__(16) char SMEM[FPS_SMEM];
  if (blockIdx.x < 4){
    fps_mw_seg<8,512,1024>(fcur, 4096, sind, gdmin, blockIdx.x, M0, M1, SMEM);
    return;
  }
  int l = blockIdx.x - 4;
  if (l < KNB){
    knn_body<8,512>(cand, n, qsrc, qidx, m, nbrOut, outc, l/NQB, l%NQB, qoff, SMEM);
    return;
  }
  l -= KNB;
  gemm_body_g<DUAL,BN>(A,B,out0,out1,Mg,Ng,Kd,lda,ldb,ldo,boff,part,invR, l%nbx, l/nbx, SMEM);
}

// [fps0 seg | knn8 slice | gather] @512
__global__ __launch_bounds__(512,2) void fps0_gather_knn(
    const float* fcur, int* sind, float* gdmin, int M0, int M1,
    const float* cand, int n, const float* qsrc, const int* qidx, int m,
    int* nbrOut, float* outc, int qoff, int NQB, int KNB,
    const float* P, const int* nbr, const float* addA, const float* addB,
    float* out, int n_out, int n_src, int O, int K, int total)
{
  __shared__ __align__(16) char SMEM[FPS_SMEM];
  if (blockIdx.x < 4){
    fps_mw_seg<8,512,1024>(fcur, 4096, sind, gdmin, blockIdx.x, M0, M1, SMEM);
    return;
  }
  int l = blockIdx.x - 4;
  if (l < KNB){
    knn_body<8,512>(cand, n, qsrc, qidx, m, nbrOut, outc, l/NQB, l%NQB, qoff, SMEM);
    return;
  }
  int e = (l-KNB)*512 + threadIdx.x;
  gather_elem(P, nbr, addA, addB, out, n_out, n_src, O, K, total, e);
}

// [fps0 seg | knn8 slice | stats_part] @512
__global__ __launch_bounds__(512,2) void fps0_stats_knn(
    const float* fcur, int* sind, float* gdmin, int M0, int M1,
    const float* cand, int n, const float* qsrc, const int* qidx, int m,
    int* nbrOut, float* outc, int qoff, int NQB, int KNB,
    const float* __restrict__ x, int R, int O, float* __restrict__ part)
{
  __shared__ __align__(16) char SMEM[FPS_SMEM];
  if (blockIdx.x < 4){
    fps_mw_seg<8,512,1024>(fcur, 4096, sind, gdmin, blockIdx.x, M0, M1, SMEM);
    return;
  }
  int l = blockIdx.x - 4;
  if (l < KNB){
    knn_body<8,512>(cand, n, qsrc, qidx, m, nbrOut, outc, l/NQB, l%NQB, qoff, SMEM);
    return;
  }
  int o = threadIdx.x;
  if (o >= O) return;
  int chunk = l - KNB;
  int per = (R + NCHUNK - 1)/NCHUNK;
  int r0 = chunk*per, r1 = min(r0+per, R);
  float s=0, q=0;
  for (int r=r0; r<r1; r++){ float v = x[(size_t)r*O + o]; s+=v; q+=v*v; }
  part[(size_t)chunk*1024 + o] = s;
  part[(size_t)(NCHUNK+chunk)*1024 + o] = q;
}

// [knn8 tail q888-1023 (136 blk) | gatherbn SAFE blocks (888: blk%256<222)] @256
__global__ __launch_bounds__(256) void knn_gatherbn_tail(
    const float* cand, int n, const float* qsrc, const int* qidx, int m,
    int* nbrOut, float* outc, int qoff, int NQB, int KNB,
    const float* P, const int* nbr, const float* part, float invR,
    float* out, float* aa, int n_out, int n_src, int O, int K)
{
  __shared__ __align__(16) char SMEM[16384];
  if (blockIdx.x < KNB){
    int l = blockIdx.x;
    knn_body<8,256>(cand, n, qsrc, qidx, m, nbrOut, outc, l/NQB, l%NQB, qoff, SMEM);
    return;
  }
  int l = blockIdx.x - KNB;           // [0,888)
  int blk = (l/222)*256 + (l%222);    // batch-correct safe-row block
  gatherbn_body(P, nbr, part, invR, out, aa, n_out, n_src, O, K, blk, SMEM);
}

// [fps1 seg0 | gatherbn UNSAFE blocks (136: blk%256>=222)] @256
__global__ __launch_bounds__(256) void fps1_gatherbn(
    const float* fcur, int* sind, float* gdmin, int M0, int M1,
    const float* P, const int* nbr, const float* part, float invR,
    float* out, float* aa, int n_out, int n_src, int O, int K)
{
  __shared__ __align__(16) char SMEM[16384];
  if (blockIdx.x < 4){
    if (threadIdx.x < 64) fps_sw_seg<16,256>(fcur, 1024, sind, gdmin, blockIdx.x, M0, M1, SMEM);
    return;
  }
  int l = blockIdx.x - 4;             // [0,136)
  int blk = (l/34)*256 + 222 + (l%34);
  gatherbn_body(P, nbr, part, invR, out, aa, n_out, n_src, O, K, blk, SMEM);
}

// [fps1 seg | Gram] @256
__global__ __launch_bounds__(256) void fps1_gram(
    const float* fcur, int* sind, float* gdmin, int M0, int M1,
    const float* Ag, float* outg, int Mg, int Kg, long sAg, long sOg, int ngx, int ngy)
{
  __shared__ __align__(16) char SMEM[16896];
  if (blockIdx.x < 4){
    if (threadIdx.x < 64) fps_sw_seg<16,256>(fcur, 1024, sind, gdmin, blockIdx.x, M0, M1, SMEM);
    return;
  }
  int l = blockIdx.x - 4;
  int bx = l % ngx, by = (l/ngx) % ngy, bz = l/(ngx*ngy);
  gemm_body<false,false>(Ag,Ag,outg,nullptr,Mg,Mg,Kg,Kg,Kg,Mg,0,sAg,sAg,sOg,nullptr,0.f,bx,by,bz,SMEM);
}

// [fps1 seg | topk] @256
__global__ __launch_bounds__(256) void fps1_topk(
    const float* fcur, int* sind, float* gdmin, int M0, int M1,
    const float* G, const float* aa, int m, int* nbr)
{
  __shared__ __align__(16) char SMEM[16384];
  if (blockIdx.x < 4){
    if (threadIdx.x < 64) fps_sw_seg<16,256>(fcur, 1024, sind, gdmin, blockIdx.x, M0, M1, SMEM);
    return;
  }
  int l = blockIdx.x - 4;
  int qpb = m/4;
  topk_body<8>(G, aa, m, nbr, l/qpb, l%qpb, SMEM);
}

// combo: [fps_sw | gather] @256
template<int NP, int M>
__global__ __launch_bounds__(256) void fps_gather(
    const float* fcur, int fn, int* sind,
    const float* P, const int* nbr, const float* addA, const float* addB,
    float* out, int n_out, int n_src, int O, int K, int total)
{
  __shared__ __align__(16) char SMEM[(NP*64*16 > 4096) ? NP*64*16 : 4096];
  if (blockIdx.x < 4){
    if (threadIdx.x < 64) fps_sw_body<NP,M>(fcur, fn, sind, blockIdx.x, SMEM);
    return;
  }
  gather_elem(P, nbr, addA, addB, out, n_out, n_src, O, K, total, (blockIdx.x-4)*256 + threadIdx.x);
}

// combo: [knn8 | gemm] @256, template DUAL/BN
template<bool DUAL, bool BN>
__global__ __launch_bounds__(256) void knn_gemm2(
    const float* cand, int n, const float* qsrc, const int* qidx, int m,
    int* nbrOut, float* outc, int KNB,
    const float* A, const float* B, float* out0, float* out1,
    int Mg, int Ng, int Kd, int boff,
    const float* part, float invR, int nbx)
{
  __shared__ __align__(16) char SMEM[16896];
  if (blockIdx.x < KNB){
    int qpb = m/4;
    knn_body<8,256>(cand, n, qsrc, qidx, m, nbrOut, outc, blockIdx.x/qpb, blockIdx.x%qpb, 0, SMEM);
    return;
  }
  int l = blockIdx.x - KNB;
  gemm_body<DUAL,BN>(A,B,out0,out1,Mg,Ng,Kd,Kd,DUAL?2*Kd:Kd,Ng,boff,0,0,0,part,invR, l%nbx, l/nbx, 0, SMEM);
}

// combo: [knn8 | gatherbn] @256
__global__ __launch_bounds__(256) void knn_gatherbn(
    const float* cand, int n, const float* qsrc, const int* qidx, int m,
    int* nbrOut, int KNB,
    const float* P, const int* nbr, const float* part, float invR,
    float* out, float* aa, int n_out, int n_src, int O, int K)
{
  __shared__ __align__(16) char SMEM[16384];
  if (blockIdx.x < KNB){
    int qpb = m/4;
    knn_body<8,256>(cand, n, qsrc, qidx, m, nbrOut, nullptr, blockIdx.x/qpb, blockIdx.x%qpb, 0, SMEM);
    return;
  }
  gatherbn_body(P, nbr, part, invR, out, aa, n_out, n_src, O, K, blockIdx.x-KNB, SMEM);
}

// combo: [Gram | gemm1 (DUAL)] @256
__global__ __launch_bounds__(256) void gram_gemm(
    const float* Ag, float* outg, int Mg, int Kg, long sAg, long sOg,
    int ngx, int ngy, int NG,
    const float* A2, const float* B2, float* o20, float* o21,
    int M2, int N2, int K2, int boff2, int nb2x)
{
  __shared__ __align__(16) char SMEM[16896];
  int l = blockIdx.x;
  if (l < NG){
    int bx = l % ngx, by = (l/ngx) % ngy, bz = l/(ngx*ngy);
    gemm_body<false,false>(Ag,Ag,outg,nullptr,Mg,Mg,Kg,Kg,Kg,Mg,0,sAg,sAg,sOg,nullptr,0.f,bx,by,bz,SMEM);
    return;
  }
  l -= NG;
  gemm_body<true,false>(A2,B2,o20,o21,M2,N2,K2,K2,2*K2,N2,boff2,0,0,0,nullptr,0.f, l%nb2x, l/nb2x, 0, SMEM);
}

// fused gemm2(BN) + shortcut-gemm
__global__ __launch_bounds__(256) void gemm2sc(
    const float* A2, const float* B2, float* o20, float* o21, int R, int O2, int O1v,
    const float* part, float invR,
    const float* Asc, const float* Bsc, float* osc, int Cin,
    int nbx, int nby)
{
  __shared__ __align__(16) char SMEM[16896];
  int l = blockIdx.x;
  int half = nbx*nby;
  if (l < half){
    gemm_body<true,true>(A2,B2,o20,o21,R,O2,O1v,O1v,2*O1v,O2,O1v,0,0,0,part,invR, l%nbx, l/nbx, 0, SMEM);
  } else {
    l -= half;
    gemm_body<false,false>(Asc,Bsc,osc,nullptr,R,O2,Cin,Cin,Cin,O2,0,0,0,0,nullptr,0.f, l%nbx, l/nbx, 0, SMEM);
  }
}

__global__ __launch_bounds__(256) void gathermax_kernel(
    const float* P, const int* nbr, const float* addA, const float* addB,
    float* out, int n_out, int n_src, int O, int K, int total)
{
  gather_elem(P, nbr, addA, addB, out, n_out, n_src, O, K, total, blockIdx.x*256 + threadIdx.x);
}

__global__ __launch_bounds__(256) void gatherbn_kernel(
    const float* P, const int* nbr, const float* part, float invR,
    float* out, float* aa, int n_out, int n_src, int O, int K)
{
  __shared__ __align__(16) char SMEM[3072];
  gatherbn_body(P, nbr, part, invR, out, aa, n_out, n_src, O, K, blockIdx.x, SMEM);
}

// standalone top-K
template<int K>
__global__ __launch_bounds__(256) void topk_wave(
    const float* __restrict__ G, const float* __restrict__ aa, int m,
    int* __restrict__ nbr)
{
  __shared__ __align__(16) char SMEM[4096];
  topk_body<K>(G, aa, m, nbr, blockIdx.y, blockIdx.x, SMEM);
}

__global__ void stats_part_kernel(const float* __restrict__ x, int R, int O,
                                  float* __restrict__ part)
{
  int o = threadIdx.x;
  int chunk = blockIdx.x;
  int per = (R + NCHUNK - 1)/NCHUNK;
  int r0 = chunk*per, r1 = min(r0+per, R);
  float s=0, q=0;
  for (int r=r0; r<r1; r++){ float v = x[(size_t)r*O + o]; s+=v; q+=v*v; }
  part[(size_t)chunk*1024 + o] = s;
  part[(size_t)(NCHUNK+chunk)*1024 + o] = q;
}

// head with BN+gelu folded on load
__global__ __launch_bounds__(1024) void head_kernel(const float* __restrict__ h,
    const float* __restrict__ part, float invR,
    const float* __restrict__ w1, const float* __restrict__ w2,
    const float* __restrict__ b2, float* __restrict__ out)
{
  __shared__ __align__(16) float mu_s[512], var_s[512];
  __shared__ __align__(16) float g[4*512];
  __shared__ __align__(16) float t[4*256];
  int tid = threadIdx.x;
  for (int oo=tid; oo<512; oo+=1024){
    float s=0, q=0;
    #pragma unroll 4
    for (int c=0;c<NCHUNK;c++){
      s += part[(size_t)c*1024 + oo];
      q += part[(size_t)(NCHUNK+c)*1024 + oo];
    }
    float mu = s*invR;
    mu_s[oo] = mu;
    var_s[oo] = q*invR - mu*mu;
  }
  __syncthreads();
  for (int e=tid; e<2048; e+=1024){
    int b=e>>9, c=e&511;
    float mu = mu_s[c], sd = sqrtf(var_s[c] + 1e-5f);
    float s=0;
    for (int p=0;p<16;p++){
      float v = h[((size_t)(b*16+p))*512 + c];
      s += gelu_f((v-mu)/sd);
    }
    g[e] = s * (1.0f/16.0f);
  }
  __syncthreads();
  {
    int b = tid>>8, j = tid&255;
    const float4* gr = (const float4*)(g + b*512);
    const float4* wr = (const float4*)(w1 + (size_t)j*512);
    float s=0;
    for (int c=0;c<128;c++){
      float4 a=gr[c], w=wr[c];
      s = fmaf(a.x,w.x, fmaf(a.y,w.y, fmaf(a.z,w.z, fmaf(a.w,w.w, s))));
    }
    t[tid] = s;
  }
  __syncthreads();
  if (tid < 256){
    float v0=t[tid], v1=t[256+tid], v2=t[512+tid], v3=t[768+tid];
    float mu = ((v0+v1)+v2+v3)*0.25f;
    float d0=v0-mu, d1=v1-mu, d2=v2-mu, d3=v3-mu;
    float var = ((d0*d0+d1*d1)+d2*d2+d3*d3)*0.25f;
    float sq = sqrtf(var + 1e-5f);
    t[tid]     = gelu_f(d0/sq);
    t[256+tid] = gelu_f(d1/sq);
    t[512+tid] = gelu_f(d2/sq);
    t[768+tid] = gelu_f(d3/sq);
  }
  __syncthreads();
  if (tid < 160){
    int b = tid/40, o = tid%40;
    const float* tr = t + b*256; const float* wr = w2 + (size_t)o*256;
    float s=0;
    for (int j=0;j<256;j++) s = fmaf(tr[j], wr[j], s);
    out[tid] = s + b2[o];
  }
}

// =====================================================================
extern "C" void kernel_launch(void* const* d_in, const int* in_sizes, int n_in,
                              void* d_out, int out_size, void* d_ws, size_t ws_size,
                              hipStream_t stream)
{
  const float* x    = (const float*)d_in[0];
  const float* xyz  = (const float*)d_in[1];
  const float* mlpw = (const float*)d_in[2];
  const float* mlpb = (const float*)d_in[3];
  const float* c0l1 = (const float*)d_in[4];
  const float* c0l2 = (const float*)d_in[5];
  const float* L1[4] = {(const float*)d_in[6], (const float*)d_in[8],
                        (const float*)d_in[11], (const float*)d_in[14]};
  const float* L2[4] = {(const float*)d_in[7], (const float*)d_in[9],
                        (const float*)d_in[12], (const float*)d_in[15]};
  const float* SC[4] = {nullptr, (const float*)d_in[10],
                        (const float*)d_in[13], (const float*)d_in[16]};
  const float* hw1 = (const float*)d_in[17];
  const float* hw2 = (const float*)d_in[18];
  const float* hb2 = (const float*)d_in[19];
  float* out = (float*)d_out;

  float* ws = (float*)d_ws;
  const size_t MF = 1024*1024;
  float* D    = ws;               // 4M floats (Gram)
  float* hA   = ws + 4*MF;
  float* hX   = ws + 5*MF;
  float* hP   = ws + 6*MF;
  float* hCT  = ws + 7*MF;
  float* hSH  = ws + 8*MF;
  float* hH1  = ws + 9*MF;
  float* hOUT = ws + 10*MF;
  float* aux  = ws + 11*MF;
  int*   nbr0  = (int*)aux;                 aux += 262144;
  int*   nbrS0 = (int*)aux;                 aux += 32768;
  int*   nbrS1 = (int*)aux;                 aux += 8192;
  int*   nbrS2 = (int*)aux;                 aux += 2048;
  int*   nbrS3 = (int*)aux;                 aux += 512;
  int*   nbrF  = (int*)aux;                 aux += 32768;
  int*   sind0 = (int*)aux;                 aux += 4096;
  int*   sind1 = (int*)aux;                 aux += 1024;
  int*   sind2 = (int*)aux;                 aux += 256;
  int*   sind3 = (int*)aux;                 aux += 64;
  float* aa    = aux;                       aux += 4096;
  float* cur1  = aux;                       aux += 12288;
  float* cur2  = aux;                       aux += 3072;
  float* cur3  = aux;                       aux += 768;
  float* part  = aux;                       aux += 65536;
  float* gdmin = aux;                       aux += 16384;

  int tot0 = 4*4096*64;

  // ---- fps0 windows with ec0 chain + query-sliced knn8 riding along ----
  // W1: fps 0-340 | knn16 | mlp
  mega1<<<4100, 512, 0, stream>>>(xyz, x, mlpw, mlpb, sind0, gdmin, nbr0, hA, 0, 340);
  stats_part_kernel<<<NCHUNK, 64, 0, stream>>>(hA, 16384, 64, part);
  // W2: fps 340-388 | bngelu(hA)
  fps_bngelu<<<4+2048, 512, 0, stream>>>(xyz, sind0, gdmin, 340, 388, hA, part, 1.0f/16384.0f, 64, tot0);
  // W3: fps 388-530 | knn8 q0-255 (NQB=32,KNB=128; needs 255<388) | ec0 gemm1
  fps0_gemm_knn<true,false><<<4+128+256, 512, 0, stream>>>(xyz, sind0, gdmin, 388, 530,
      xyz, 4096, xyz, sind0, 1024, nbrS0, cur1, 0, 32, 128,
      hA, c0l1, hP, hCT, 16384, 64, 64, 64, 128, 64, 64, nullptr, 0.f, 1);
  // W4: fps 530-710 | knn8 q256-511 (NQB=32,KNB=128; needs 511<530) | ec0 gather1
  fps0_gather_knn<<<4+128+2048, 512, 0, stream>>>(xyz, sind0, gdmin, 530, 710,
      xyz, 4096, xyz, sind0, 1024, nbrS0, cur1, 256, 32, 128,
      hP, nbr0, hCT, nullptr, hH1, 4096, 4096, 64, 16, 1048576);
  stats_part_kernel<<<NCHUNK, 64, 0, stream>>>(hH1, 16384, 64, part);
  // W5: fps 710-790 | knn8 q512-655 (NQB=18,KNB=72; needs 655<710) | ec0 gemm2 (BN)
  fps0_gemm_knn<true,true><<<4+72+256, 512, 0, stream>>>(xyz, sind0, gdmin, 710, 790,
      xyz, 4096, xyz, sind0, 1024, nbrS0, cur1, 512, 18, 72,
      hH1, c0l2, hP, hCT, 16384, 64, 64, 64, 128, 64, 64, part, 1.0f/16384.0f, 1);
  // W6: fps 790-900 | knn8 q656-783 (NQB=16,KNB=64; needs 783<790) | ec0 gather2 (+hA)
  fps0_gather_knn<<<4+64+2048, 512, 0, stream>>>(xyz, sind0, gdmin, 790, 900,
      xyz, 4096, xyz, sind0, 1024, nbrS0, cur1, 656, 16, 64,
      hP, nbr0, hCT, hA, hOUT, 4096, 4096, 64, 16, 1048576);
  // W7: fps 900-1024 | knn8 q784-887 (NQB=13,KNB=52; needs 887<900) | stats(hOUT)
  fps0_stats_knn<<<4+52+NCHUNK, 512, 0, stream>>>(xyz, sind0, gdmin, 900, 1024,
      xyz, 4096, xyz, sind0, 1024, nbrS0, cur1, 784, 13, 52,
      hOUT, 16384, 64, part);
  // fps0 complete; hOUT = ec0 output (raw) + stats in part

  // ---- stage0 pre ----
  // Tail: [knn8 q888-1023 (NQB=34, KNB=136 @256thr) | gatherbn SAFE rows (888 blk)]
  knn_gatherbn_tail<<<136+888, 256, 0, stream>>>(
      xyz, 4096, xyz, sind0, 1024, nbrS0, cur1, 888, 34, 136,
      hOUT, nbrS0, part, 1.0f/16384.0f, hX, aa, 1024, 4096, 64, 8);
  // [fps1 seg0 0-86 | gatherbn UNSAFE rows (136 blk, i>=888)]
  fps1_gatherbn<<<4+136, 256, 0, stream>>>(cur1, sind1, gdmin, 0, 86,
      hOUT, nbrS0, part, 1.0f/16384.0f, hX, aa, 1024, 4096, 64, 8);
  // [fps1 seg1 86-171 | Gram0]
  fps1_gram<<<4+1024, 256, 0, stream>>>(cur1, sind1, gdmin, 86, 171,
      hX, D, 1024, 64, (long)1024*64, (long)1024*1024, 16, 16);
  // [fps1 seg2 171-256 | topk m=1024]
  fps1_topk<<<4+1024, 256, 0, stream>>>(cur1, sind1, gdmin, 171, 256,
      D, aa, 1024, nbrF);
  // [knn8_1 (m=256 vs cur1; needs full sind1) | s0 gemm1]
  knn_gemm2<true,false><<<256+64,256,0,stream>>>(cur1, 1024, cur1, sind1, 256,
      nbrS1, cur2, 256,
      hX, L1[0], hP, hCT, 4096, 64, 64, 64, nullptr, 0.f, 1);
  // [fps2 (cur2, 256->64) | s0 gather1]
  fps_gather<4,64><<<4+1024,256,0,stream>>>(cur2, 256, sind2,
      hP, nbrF, hCT, nullptr, hH1, 1024, 1024, 64, 8, 262144);
  stats_part_kernel<<<NCHUNK, 64, 0, stream>>>(hH1, 4096, 64, part);
  // [knn8_2 (m=64 vs cur2) | s0 gemm2 BN]
  knn_gemm2<true,true><<<64+64,256,0,stream>>>(cur2, 256, cur2, sind2, 64,
      nbrS2, cur3, 64,
      hH1, L2[0], hP, hCT, 4096, 64, 64, 64, part, 1.0f/4096.0f, 1);
  // [fps3 (cur3, 64->16) | s0 gather2 (+hX residual)]
  fps_gather<1,16><<<4+1024,256,0,stream>>>(cur3, 64, sind3,
      hP, nbrF, hCT, hX, hA, 1024, 1024, 64, 8, 262144);
  stats_part_kernel<<<NCHUNK, 64, 0, stream>>>(hA, 4096, 64, part);
  // [knn8_3 (m=16 vs cur3) | stage1 gatherbn hA->hX + aa]
  knn_gatherbn<<<16+256,256,0,stream>>>(cur3, 64, cur3, sind3, 16,
      nbrS3, 16,
      hA, nbrS1, part, 1.0f/4096.0f, hX, aa, 256, 1024, 64, 8);
  // hX = stage1 downsampled input (post-BN), aa = norms

  // ---- stages 1-3 (geometry precomputed) ----
  const int   mArr[3]   = {256, 64, 16};
  const int   nsrcArr[3]= {1024, 256, 64};
  const int   CinArr[3] = {64, 128, 256};
  const int   OArr[3]   = {128, 256, 512};
  const int*  nbrSs[3]  = {nbrS1, nbrS2, nbrS3};
  float* hcur = hA;
  float invRprev = 1.0f/4096.0f;
  for (int s=0;s<3;s++){
    int m = mArr[s], nsrc = nsrcArr[s], Cin = CinArr[s], O1 = OArr[s], O2 = OArr[s];
    int R = 4*m;
    int th = R*Cin;
    if (s > 0){
      gatherbn_kernel<<<th/256,256,0,stream>>>(hcur, nbrSs[s], part, invRprev,
                                               hX, aa, m, nsrc, Cin, 8);
    }
    int ngx = (m+63)/64, ngy = (m+63)/64;
    int NG = ngx*ngy*4;
    int nb1x = (O1+63)/64, nb1y = (R+63)/64;
    gram_gemm<<<NG + nb1x*nb1y, 256, 0, stream>>>(
        hX, D, m, Cin, (long)m*Cin, (long)m*m, ngx, ngy, NG,
        hX, L1[s+1], hP, hCT, R, O1, Cin, Cin, nb1x);
    topk_wave<8><<<dim3(m/4,4),256,0,stream>>>(D, aa, m, nbrF);
    int t1 = R*O1;
    gathermax_kernel<<<(t1+255)/256,256,0,stream>>>(hP, nbrF, hCT, nullptr, hH1, m, m, O1, 8, t1);
    stats_part_kernel<<<NCHUNK, O1, 0, stream>>>(hH1, R, O1, part);
    int nbx = (O2+63)/64, nby = (R+63)/64;
    gemm2sc<<<2*nbx*nby,256,0,stream>>>(hH1, L2[s+1], hP, hCT, R, O2, O1, part, 1.0f/R,
                                        hX, SC[s+1], hSH, Cin, nbx, nby);
    int t2 = R*O2;
    float* outbuf = (s&1) ? hA : hOUT;
    gathermax_kernel<<<(t2+255)/256,256,0,stream>>>(hP, nbrF, hCT, hSH, outbuf, m, m, O2, 8, t2);
    stats_part_kernel<<<NCHUNK, O2, 0, stream>>>(outbuf, R, O2, part);
    hcur = outbuf;
    invRprev = 1.0f/R;
  }

  head_kernel<<<1,1024,0,stream>>>(hcur, part, 1.0f/64.0f, hw1, hw2, hb2, out);
}

// Round 21
// 1497.942 us; speedup vs baseline: 1.0261x; 1.0261x over previous
//
#include <hip/hip_runtime.h>
#include <math.h>

#define NCHUNK 32
typedef unsigned long long ull;

__device__ __forceinline__ float gelu_f(float v){
  return 0.5f*v*(1.0f+erff(v*0.70710678118654752440f));
}

__device__ __forceinline__ unsigned flipf(float d){
  unsigned u = __float_as_uint(d);
  return (u & 0x80000000u) ? ~u : (u | 0x80000000u);
}

// ---- DPP helpers ----
template<int CTRL>
__device__ __forceinline__ ull dpp64(ull k){
  int lo = __builtin_amdgcn_update_dpp(0, (int)(unsigned)k,       CTRL, 0xF, 0xF, true);
  int hi = __builtin_amdgcn_update_dpp(0, (int)(unsigned)(k>>32), CTRL, 0xF, 0xF, true);
  return ((ull)(unsigned)hi<<32) | (unsigned)lo;
}
__device__ __forceinline__ ull rl64(ull k, int l){
  unsigned lo = (unsigned)__builtin_amdgcn_readlane((int)(unsigned)k, l);
  unsigned hi = (unsigned)__builtin_amdgcn_readlane((int)(unsigned)(k>>32), l);
  return ((ull)hi<<32) | lo;
}
// FPS keys: hi = float bits of nd>=0 -> u64 order == f64 order (positive doubles).
__device__ __forceinline__ ull fmax64(ull a, ull b){
  return (ull)__double_as_longlong(fmax(__longlong_as_double((long long)a),
                                        __longlong_as_double((long long)b)));
}
__device__ __forceinline__ ull wave_fmax(ull k){
  k = fmax64(k, dpp64<0xB1>(k));
  k = fmax64(k, dpp64<0x4E>(k));
  k = fmax64(k, dpp64<0x141>(k));
  k = fmax64(k, dpp64<0x140>(k));
  ull a=rl64(k,0), b=rl64(k,16), c=rl64(k,32), d=rl64(k,48);
  return fmax64(fmax64(a,b), fmax64(c,d));
}
// kNN keys are positive doubles (flip*4096+j) -> f64 min directly.
template<int CTRL>
__device__ __forceinline__ double dmin_dpp(double k){
  ull o = dpp64<CTRL>((ull)__double_as_longlong(k));
  return fmin(k, __longlong_as_double((long long)o));
}
__device__ __forceinline__ double wave_dmin(double k){
  k = dmin_dpp<0xB1>(k);
  k = dmin_dpp<0x4E>(k);
  k = dmin_dpp<0x141>(k);
  k = dmin_dpp<0x140>(k);
  ull kb = (ull)__double_as_longlong(k);
  double a = __longlong_as_double((long long)rl64(kb,0));
  double b = __longlong_as_double((long long)rl64(kb,16));
  double c = __longlong_as_double((long long)rl64(kb,32));
  double d = __longlong_as_double((long long)rl64(kb,48));
  return fmin(fmin(a,b), fmin(c,d));
}

// ================= device bodies =================

// ---- wave-per-query kNN; key = flip(d)*4096 + j (exact f64, lex order) ----
template<int K, int T>
__device__ __forceinline__ void knn_body(
    const float* __restrict__ cand, int n,
    const float* __restrict__ qsrc, const int* __restrict__ qidx, int m,
    int* __restrict__ nbr, float* __restrict__ outc,
    int b, int qblk, int qoff, char* smem)
{
  float4* tile = (float4*)smem;   // 1024 entries, 16KB
  constexpr int NWV = T/64;
  int wv = threadIdx.x >> 6, lane = threadIdx.x & 63;
  int q = qblk*NWV + wv + qoff;
  const float* cb = cand + (size_t)b*3*n;
  int qi = qidx ? qidx[(size_t)b*m + q] : q;
  const float* qb = qsrc + (size_t)b*3*n;
  float qx = qb[qi], qy = qb[n+qi], qz = qb[2*n+qi];
  float aa = (qx*qx + qy*qy) + qz*qz;

  double a[K];
  #pragma unroll
  for (int k=0;k<K;k++) a[k] = 1e300;

  for (int base=0; base<n; base+=1024){
    int cnt = min(1024, n-base);
    for (int j=threadIdx.x; j<cnt; j+=T){
      float x=cb[base+j], y=cb[n+base+j], z=cb[2*n+base+j];
      tile[j] = make_float4(x,y,z,(x*x+y*y)+z*z);
    }
    __syncthreads();
    int steps = cnt >> 6;
    double jd = (double)(base + lane);
    for (int i=0;i<steps;i++){
      int j = lane + (i<<6);
      float4 c = tile[j];
      float d = aa + c.w - 2.0f*((qx*c.x+qy*c.y)+qz*c.z);
      double key = (double)flipf(d) * 4096.0 + jd;
      if (key < a[K-1]){
        #pragma unroll
        for (int k=K-1;k>=1;k--)
          a[k] = fmin(fmax(a[k-1], key), a[k]);
        a[0] = fmin(a[0], key);
      }
      jd += 64.0;
    }
    __syncthreads();
  }

  double head = a[0];
  int res[K];
  #pragma unroll
  for (int r=0; r<K; r++){
    double mk = wave_dmin(head);
    res[r] = (int)((ull)mk & 4095u);
    if (head == mk){
      #pragma unroll
      for (int i2=0;i2<K-1;i2++) a[i2]=a[i2+1];
      a[K-1] = 1e300;
      head = a[0];
    }
  }
  if (lane == 0){
    int* o = nbr + ((size_t)b*m + q)*K;
    #pragma unroll
    for (int r=0;r<K;r++) o[r] = res[r];
  }
  if (outc != nullptr && lane < 3){
    const float* cd = cb + (size_t)lane*n;
    float s=0;
    #pragma unroll
    for (int k=0;k<K;k++) s += cd[res[k]];
    outc[((size_t)b*3 + lane)*m + q] = s * (1.0f/K);
  }
}

// ---- top-K from Gram rows (f64 keys) body ----
template<int K>
__device__ __forceinline__ void topk_body(
    const float* __restrict__ G, const float* __restrict__ aa, int m,
    int* __restrict__ nbr, int b, int qblk, char* smem)
{
  float* abs_s = (float*)smem;
  int wv = threadIdx.x >> 6, lane = threadIdx.x & 63;
  int q = qblk*4 + wv;
  const float* ab = aa + (size_t)b*m;
  for (int j=threadIdx.x; j<m; j+=256) abs_s[j] = ab[j];
  __syncthreads();
  float aq = ab[q];
  const float* Gq = G + ((size_t)b*m + q)*m;

  double a[K];
  #pragma unroll
  for (int k=0;k<K;k++) a[k] = 1e300;

  int steps = (m+63)>>6;
  double jd = (double)lane;
  for (int i=0;i<steps;i++){
    int j = lane + (i<<6);
    double key = 1e300;
    if (j < m){
      float g = Gq[j];
      float d = aq + abs_s[j] - 2.0f*g;
      key = (double)flipf(d) * 4096.0 + jd;
    }
    if (key < a[K-1]){
      #pragma unroll
      for (int k=K-1;k>=1;k--)
        a[k] = fmin(fmax(a[k-1], key), a[k]);
      a[0] = fmin(a[0], key);
    }
    jd += 64.0;
  }
  double head = a[0];
  int res[K];
  #pragma unroll
  for (int r=0; r<K; r++){
    double mk = wave_dmin(head);
    res[r] = (int)((ull)mk & 4095u);
    if (head == mk){
      #pragma unroll
      for (int i2=0;i2<K-1;i2++) a[i2]=a[i2+1];
      a[K-1] = 1e300;
      head = a[0];
    }
  }
  if (lane == 0){
    int* o = nbr + ((size_t)b*m + q)*K;
    #pragma unroll
    for (int r=0;r<K;r++) o[r] = res[r];
  }
}

// ---- segmented multi-wave FPS (stage 0) ----
template<int NP, int T, int M>
__device__ __forceinline__ void fps_mw_seg(const float* __restrict__ cur, int n,
                                           int* __restrict__ sind, float* __restrict__ gdmin,
                                           int b, int M0, int M1, char* smem)
{
  constexpr int NW = T/64;
  int tid = threadIdx.x;
  int wv = tid>>6;
  const float* cb = cur + (size_t)b*3*n;
  float4* lp = (float4*)smem;
  ull* wred = (ull*)(smem + sizeof(float4)*NP*T);
  float* gd = gdmin + (size_t)b*n;
  float px[NP], py[NP], pz[NP], dmin[NP];
  unsigned nj[NP];
  #pragma unroll
  for (int s=0;s<NP;s++){
    int j = tid + s*T;
    px[s]=cb[j]; py[s]=cb[n+j]; pz[s]=cb[2*n+j];
    dmin[s] = (M0==0) ? 1e30f : gd[j];
    nj[s] = (unsigned)(~j);
    lp[j] = make_float4(px[s],py[s],pz[s],0.f);
  }
  __syncthreads();
  int ci = (M0==0) ? 0 : sind[(size_t)b*M + (M0-1)];
  float4 w0 = lp[ci];
  float X = w0.x, Y = w0.y, Z = w0.z;
  if (M0==0 && tid==0) sind[(size_t)b*M] = 0;
  __builtin_amdgcn_s_setprio(3);
  int p = 0;
  int s0 = (M0==0) ? 1 : M0;
  for (int step=s0; step<M1; step++){
    ull key[NP];
    #pragma unroll
    for (int s=0;s<NP;s++){
      float dx=px[s]-X, dy=py[s]-Y, dz=pz[s]-Z;
      float d = (dx*dx + dy*dy) + dz*dz;
      float nd = fminf(dmin[s], d);
      dmin[s] = nd;
      key[s] = ((ull)__float_as_uint(nd)<<32) | nj[s];
    }
    #pragma unroll
    for (int w=NP; w>1; w>>=1)
      #pragma unroll
      for (int i=0;i<NP;i++) if (i < (w>>1))
        key[i] = fmax64(key[i], key[i+(w>>1)]);
    ull wk = wave_fmax(key[0]);
    if ((tid&63)==0) wred[p*NW + wv] = wk;
    __syncthreads();
    const ulonglong2* wp2 = (const ulonglong2*)(wred + p*NW);
    ulonglong2 m0 = wp2[0], m1 = wp2[1], m2 = wp2[2], m3 = wp2[3];
    ull gk = fmax64(fmax64(fmax64(m0.x,m0.y), fmax64(m1.x,m1.y)),
                    fmax64(fmax64(m2.x,m2.y), fmax64(m3.x,m3.y)));
    int gi = (int)(~(unsigned)gk);
    if (tid==0) sind[(size_t)b*M + step] = gi;
    float4 wp = lp[gi];
    X=wp.x; Y=wp.y; Z=wp.z;
    p ^= 1;
  }
  __builtin_amdgcn_s_setprio(0);
  #pragma unroll
  for (int s=0;s<NP;s++) gd[tid + s*T] = dmin[s];
}

// ---- single-wave FPS (non-segmented) ----
template<int NP, int M>
__device__ __forceinline__ void fps_sw_body(const float* __restrict__ cur, int n,
                                            int* __restrict__ sind, int b, char* smem)
{
  int lane = threadIdx.x;
  const float* cb = cur + (size_t)b*3*n;
  float4* lp = (float4*)smem;
  float px[NP], py[NP], pz[NP], dmin[NP];
  unsigned nj[NP];
  #pragma unroll
  for (int s=0;s<NP;s++){
    int j = lane + s*64;
    px[s]=cb[j]; py[s]=cb[n+j]; pz[s]=cb[2*n+j]; dmin[s]=1e30f;
    nj[s] = (unsigned)(~j);
    lp[j] = make_float4(px[s],py[s],pz[s],0.f);
  }
  float X = lp[0].x, Y = lp[0].y, Z = lp[0].z;
  if (lane==0) sind[(size_t)b*M] = 0;
  __builtin_amdgcn_s_setprio(3);
  for (int step=1; step<M; step++){
    ull key[NP];
    #pragma unroll
    for (int s=0;s<NP;s++){
      float dx=px[s]-X, dy=py[s]-Y, dz=pz[s]-Z;
      float d = (dx*dx + dy*dy) + dz*dz;
      float nd = fminf(dmin[s], d);
      dmin[s] = nd;
      key[s] = ((ull)__float_as_uint(nd)<<32) | nj[s];
    }
    #pragma unroll
    for (int w=NP; w>1; w>>=1)
      #pragma unroll
      for (int i=0;i<NP;i++) if (i < (w>>1))
        key[i] = fmax64(key[i], key[i+(w>>1)]);
    ull gk = wave_fmax(key[0]);
    int gi = (int)(~(unsigned)gk);
    if (lane==0) sind[(size_t)b*M + step] = gi;
    float4 wp = lp[gi];
    X=wp.x; Y=wp.y; Z=wp.z;
  }
  __builtin_amdgcn_s_setprio(0);
}

// ---- single-wave FPS, segmented ----
template<int NP, int M>
__device__ __forceinline__ void fps_sw_seg(const float* __restrict__ cur, int n,
                                           int* __restrict__ sind, float* __restrict__ gdmin,
                                           int b, int M0, int M1, char* smem)
{
  int lane = threadIdx.x;
  const float* cb = cur + (size_t)b*3*n;
  float4* lp = (float4*)smem;
  float* gd = gdmin + (size_t)b*n;
  float px[NP], py[NP], pz[NP], dmin[NP];
  unsigned nj[NP];
  #pragma unroll
  for (int s=0;s<NP;s++){
    int j = lane + s*64;
    px[s]=cb[j]; py[s]=cb[n+j]; pz[s]=cb[2*n+j];
    dmin[s] = (M0==0) ? 1e30f : gd[j];
    nj[s] = (unsigned)(~j);
    lp[j] = make_float4(px[s],py[s],pz[s],0.f);
  }
  int ci = (M0==0) ? 0 : sind[(size_t)b*M + (M0-1)];
  float4 w0 = lp[ci];
  float X = w0.x, Y = w0.y, Z = w0.z;
  if (M0==0 && lane==0) sind[(size_t)b*M] = 0;
  __builtin_amdgcn_s_setprio(3);
  int s0 = (M0==0) ? 1 : M0;
  for (int step=s0; step<M1; step++){
    ull key[NP];
    #pragma unroll
    for (int s=0;s<NP;s++){
      float dx=px[s]-X, dy=py[s]-Y, dz=pz[s]-Z;
      float d = (dx*dx + dy*dy) + dz*dz;
      float nd = fminf(dmin[s], d);
      dmin[s] = nd;
      key[s] = ((ull)__float_as_uint(nd)<<32) | nj[s];
    }
    #pragma unroll
    for (int w=NP; w>1; w>>=1)
      #pragma unroll
      for (int i=0;i<NP;i++) if (i < (w>>1))
        key[i] = fmax64(key[i], key[i+(w>>1)]);
    ull gk = wave_fmax(key[0]);
    int gi = (int)(~(unsigned)gk);
    if (lane==0) sind[(size_t)b*M + step] = gi;
    float4 wp = lp[gi];
    X=wp.x; Y=wp.y; Z=wp.z;
  }
  __builtin_amdgcn_s_setprio(0);
  #pragma unroll
  for (int s=0;s<NP;s++) gd[lane + s*64] = dmin[s];
}

// ---- tiled NT GEMM body; BN variant finalizes mu/var from `part` in LDS ----
template<bool DUAL, bool BN>
__device__ __forceinline__ void gemm_body(
    const float* __restrict__ A, const float* __restrict__ B,
    float* __restrict__ out0, float* __restrict__ out1,
    int M, int N, int Kd, int lda, int ldb, int ldo, int boff,
    long sA, long sB, long sO, const float* __restrict__ part, float invR,
    int bxi, int byi, int bzi, char* smem)
{
  A += (size_t)bzi * sA; B += (size_t)bzi * sB;
  float* o0 = out0 + (size_t)bzi * sO;
  float* o1 = DUAL ? (out1 + (size_t)bzi * sO) : nullptr;
  int rowBase = byi*64, colBase = bxi*64;
  float (*As)[64]  = (float(*)[64])smem;
  float (*Bs0)[64] = (float(*)[64])(smem + 4096);
  float (*Bs1)[64] = (float(*)[64])(smem + 8192);
  float* mu_s = (float*)(smem + 12288);
  float* var_s = mu_s + 512;
  int tid = threadIdx.x;
  if (BN){
    for (int oo=tid; oo<Kd; oo+=blockDim.x){
      float s=0, q=0;
      #pragma unroll 4
      for (int c=0;c<NCHUNK;c++){
        s += part[(size_t)c*1024 + oo];
        q += part[(size_t)(NCHUNK+c)*1024 + oo];
      }
      float mu = s*invR;
      mu_s[oo] = mu;
      var_s[oo] = q*invR - mu*mu;
    }
    __syncthreads();
  }
  int ty = tid>>4, tx = tid&15;
  float acc0[4][4] = {}, acc1[4][4] = {};
  int lr = tid>>2, lk = (tid&3)*4;
  for (int k0=0; k0<Kd; k0+=16) {
    float4 va = make_float4(0,0,0,0);
    int r = rowBase + lr;
    if (r < M) va = *(const float4*)(A + (size_t)r*lda + k0 + lk);
    if (BN){
      int c = k0 + lk;
      va.x = gelu_f((va.x - mu_s[c+0]) / sqrtf(var_s[c+0] + 1e-5f));
      va.y = gelu_f((va.y - mu_s[c+1]) / sqrtf(var_s[c+1] + 1e-5f));
      va.z = gelu_f((va.z - mu_s[c+2]) / sqrtf(var_s[c+2] + 1e-5f));
      va.w = gelu_f((va.w - mu_s[c+3]) / sqrtf(var_s[c+3] + 1e-5f));
    }
    As[lk+0][lr]=va.x; As[lk+1][lr]=va.y; As[lk+2][lr]=va.z; As[lk+3][lr]=va.w;
    float4 vb = make_float4(0,0,0,0), vb2 = make_float4(0,0,0,0);
    int c2 = colBase + lr;
    if (c2 < N) {
      vb = *(const float4*)(B + (size_t)c2*ldb + k0 + lk);
      if (DUAL) vb2 = *(const float4*)(B + (size_t)c2*ldb + boff + k0 + lk);
    }
    Bs0[lk+0][lr]=vb.x; Bs0[lk+1][lr]=vb.y; Bs0[lk+2][lr]=vb.z; Bs0[lk+3][lr]=vb.w;
    if (DUAL) {
      Bs1[lk+0][lr]=vb2.x-vb.x; Bs1[lk+1][lr]=vb2.y-vb.y;
      Bs1[lk+2][lr]=vb2.z-vb.z; Bs1[lk+3][lr]=vb2.w-vb.w;
    }
    __syncthreads();
    #pragma unroll
    for (int kk=0;kk<16;kk++){
      float4 a  = *(const float4*)&As[kk][ty*4];
      float4 b0 = *(const float4*)&Bs0[kk][tx*4];
      float av[4]={a.x,a.y,a.z,a.w};
      float b0v[4]={b0.x,b0.y,b0.z,b0.w};
      #pragma unroll
      for (int i=0;i<4;i++)
        #pragma unroll
        for (int j=0;j<4;j++) acc0[i][j] = fmaf(av[i], b0v[j], acc0[i][j]);
      if (DUAL) {
        float4 b1 = *(const float4*)&Bs1[kk][tx*4];
        float b1v[4]={b1.x,b1.y,b1.z,b1.w};
        #pragma unroll
        for (int i=0;i<4;i++)
          #pragma unroll
          for (int j=0;j<4;j++) acc1[i][j] = fmaf(av[i], b1v[j], acc1[i][j]);
      }
    }
    __syncthreads();
  }
  #pragma unroll
  for (int i=0;i<4;i++){
    int r = rowBase + ty*4 + i;
    if (r < M) {
      #pragma unroll
      for (int j=0;j<4;j++){
        int c = colBase + tx*4 + j;
        if (c < N) {
          o0[(size_t)r*ldo + c] = acc0[i][j];
          if (DUAL) o1[(size_t)r*ldo + c] = acc1[i][j];
        }
      }
    }
  }
}

// ---- symmetric Gram tile body (A·Aᵀ); computes tile (by,bx) with by<=bx and
// mirror-writes the transposed tile. Full 64-multiple dims, no bounds checks. ----
__device__ __forceinline__ void gram_sym_body(
    const float* __restrict__ A, float* __restrict__ o0,
    int M, int Kd, int bxi, int byi, char* smem)
{
  int rowBase = byi*64, colBase = bxi*64;
  float (*As)[64] = (float(*)[64])smem;
  float (*Bs)[64] = (float(*)[64])(smem + 4096);
  int tid = threadIdx.x;
  int ty = tid>>4, tx = tid&15;
  float acc[4][4] = {};
  int lr = tid>>2, lk = (tid&3)*4;
  for (int k0=0; k0<Kd; k0+=16) {
    float4 va = *(const float4*)(A + (size_t)(rowBase+lr)*Kd + k0 + lk);
    As[lk+0][lr]=va.x; As[lk+1][lr]=va.y; As[lk+2][lr]=va.z; As[lk+3][lr]=va.w;
    float4 vb = *(const float4*)(A + (size_t)(colBase+lr)*Kd + k0 + lk);
    Bs[lk+0][lr]=vb.x; Bs[lk+1][lr]=vb.y; Bs[lk+2][lr]=vb.z; Bs[lk+3][lr]=vb.w;
    __syncthreads();
    #pragma unroll
    for (int kk=0;kk<16;kk++){
      float4 a  = *(const float4*)&As[kk][ty*4];
      float4 b0 = *(const float4*)&Bs[kk][tx*4];
      float av[4]={a.x,a.y,a.z,a.w};
      float b0v[4]={b0.x,b0.y,b0.z,b0.w};
      #pragma unroll
      for (int i=0;i<4;i++)
        #pragma unroll
        for (int j=0;j<4;j++) acc[i][j] = fmaf(av[i], b0v[j], acc[i][j]);
    }
    __syncthreads();
  }
  #pragma unroll
  for (int i=0;i<4;i++){
    int r = rowBase + ty*4 + i;
    #pragma unroll
    for (int j=0;j<4;j++)
      o0[(size_t)r*M + colBase + tx*4 + j] = acc[i][j];
  }
  if (bxi != byi){
    #pragma unroll
    for (int j=0;j<4;j++){
      int c = colBase + tx*4 + j;
      #pragma unroll
      for (int i=0;i<4;i++)
        o0[(size_t)c*M + rowBase + ty*4 + i] = acc[i][j];
    }
  }
}

// ---- guarded GEMM body for 512-thread co-launch ----
template<bool DUAL, bool BN>
__device__ __forceinline__ void gemm_body_g(
    const float* __restrict__ A, const float* __restrict__ B,
    float* __restrict__ out0, float* __restrict__ out1,
    int M, int N, int Kd, int lda, int ldb, int ldo, int boff,
    const float* __restrict__ part, float invR,
    int bxi, int byi, char* smem)
{
  int rowBase = byi*64, colBase = bxi*64;
  float (*As)[64]  = (float(*)[64])smem;
  float (*Bs0)[64] = (float(*)[64])(smem + 4096);
  float (*Bs1)[64] = (float(*)[64])(smem + 8192);
  float* mu_s = (float*)(smem + 12288);
  float* var_s = mu_s + 512;
  int tid = threadIdx.x;
  bool act = tid < 256;
  if (BN){
    for (int oo=tid; oo<Kd; oo+=blockDim.x){
      float s=0, q=0;
      #pragma unroll 4
      for (int c=0;c<NCHUNK;c++){
        s += part[(size_t)c*1024 + oo];
        q += part[(size_t)(NCHUNK+c)*1024 + oo];
      }
      float mu = s*invR;
      mu_s[oo] = mu;
      var_s[oo] = q*invR - mu*mu;
    }
    __syncthreads();
  }
  int ty = tid>>4, tx = tid&15;
  float acc0[4][4] = {}, acc1[4][4] = {};
  int lr = tid>>2, lk = (tid&3)*4;
  for (int k0=0; k0<Kd; k0+=16) {
    if (act){
      float4 va = make_float4(0,0,0,0);
      int r = rowBase + lr;
      if (r < M) va = *(const float4*)(A + (size_t)r*lda + k0 + lk);
      if (BN){
        int c = k0 + lk;
        va.x = gelu_f((va.x - mu_s[c+0]) / sqrtf(var_s[c+0] + 1e-5f));
        va.y = gelu_f((va.y - mu_s[c+1]) / sqrtf(var_s[c+1] + 1e-5f));
        va.z = gelu_f((va.z - mu_s[c+2]) / sqrtf(var_s[c+2] + 1e-5f));
        va.w = gelu_f((va.w - mu_s[c+3]) / sqrtf(var_s[c+3] + 1e-5f));
      }
      As[lk+0][lr]=va.x; As[lk+1][lr]=va.y; As[lk+2][lr]=va.z; As[lk+3][lr]=va.w;
      float4 vb = make_float4(0,0,0,0), vb2 = make_float4(0,0,0,0);
      int c2 = colBase + lr;
      if (c2 < N) {
        vb = *(const float4*)(B + (size_t)c2*ldb + k0 + lk);
        if (DUAL) vb2 = *(const float4*)(B + (size_t)c2*ldb + boff + k0 + lk);
      }
      Bs0[lk+0][lr]=vb.x; Bs0[lk+1][lr]=vb.y; Bs0[lk+2][lr]=vb.z; Bs0[lk+3][lr]=vb.w;
      if (DUAL) {
        Bs1[lk+0][lr]=vb2.x-vb.x; Bs1[lk+1][lr]=vb2.y-vb.y;
        Bs1[lk+2][lr]=vb2.z-vb.z; Bs1[lk+3][lr]=vb2.w-vb.w;
      }
    }
    __syncthreads();
    if (act){
      #pragma unroll
      for (int kk=0;kk<16;kk++){
        float4 a  = *(const float4*)&As[kk][ty*4];
        float4 b0 = *(const float4*)&Bs0[kk][tx*4];
        float av[4]={a.x,a.y,a.z,a.w};
        float b0v[4]={b0.x,b0.y,b0.z,b0.w};
        #pragma unroll
        for (int i=0;i<4;i++)
          #pragma unroll
          for (int j=0;j<4;j++) acc0[i][j] = fmaf(av[i], b0v[j], acc0[i][j]);
        if (DUAL) {
          float4 b1 = *(const float4*)&Bs1[kk][tx*4];
          float b1v[4]={b1.x,b1.y,b1.z,b1.w};
          #pragma unroll
          for (int i=0;i<4;i++)
            #pragma unroll
            for (int j=0;j<4;j++) acc1[i][j] = fmaf(av[i], b1v[j], acc1[i][j]);
        }
      }
    }
    __syncthreads();
  }
  if (act){
    #pragma unroll
    for (int i=0;i<4;i++){
      int r = rowBase + ty*4 + i;
      if (r < M) {
        #pragma unroll
        for (int j=0;j<4;j++){
          int c = colBase + tx*4 + j;
          if (c < N) {
            out0[(size_t)r*ldo + c] = acc0[i][j];
            if (DUAL) out1[(size_t)r*ldo + c] = acc1[i][j];
          }
        }
      }
    }
  }
}

// ---- plain gather + max ----
__device__ __forceinline__ void gather_elem(
    const float* __restrict__ P, const int* __restrict__ nbr,
    const float* __restrict__ addA, const float* __restrict__ addB,
    float* __restrict__ out, int n_out, int n_src, int O, int K, int total, int e)
{
  if (e >= total) return;
  int o = e % O; int r = e / O;
  int b = r / n_out; int i = r % n_out;
  const int* nb = nbr + ((size_t)b*n_out + i)*K;
  float mx = -1e38f;
  for (int k=0;k<K;k++){
    int j = nb[k];
    float v = P[((size_t)b*n_src + j)*O + o];
    mx = fmaxf(mx, v);
  }
  float res = mx;
  if (addA) res += addA[e];
  if (addB) res = addB[e] + res;
  out[e] = res;
}

// ---- downsample gather with BN+gelu on load + row-norm emit ----
__device__ __forceinline__ void gatherbn_body(
    const float* __restrict__ P, const int* __restrict__ nbr,
    const float* __restrict__ part, float invR,
    float* __restrict__ out, float* __restrict__ aa,
    int n_out, int n_src, int O, int K, int blk, char* smem)
{
  float* mu_s = (float*)smem; float* var_s = mu_s + 256; float* sv = var_s + 256;
  int tid = threadIdx.x;
  for (int oo=tid; oo<O; oo+=256){
    float s=0, q=0;
    #pragma unroll 4
    for (int c=0;c<NCHUNK;c++){
      s += part[(size_t)c*1024 + oo];
      q += part[(size_t)(NCHUNK+c)*1024 + oo];
    }
    float mu = s*invR;
    mu_s[oo] = mu;
    var_s[oo] = q*invR - mu*mu;
  }
  __syncthreads();
  int e = blk*256 + tid;
  int o = e % O; int r = e / O;
  int b = r / n_out; int i = r % n_out;
  const int* nb = nbr + ((size_t)b*n_out + i)*K;
  float mu = mu_s[o], sd = sqrtf(var_s[o] + 1e-5f);
  float mx = -1e38f;
  for (int k=0;k<K;k++){
    int j = nb[k];
    float p = P[((size_t)b*n_src + j)*O + o];
    float v = gelu_f((p - mu)/sd);
    mx = fmaxf(mx, v);
  }
  out[e] = mx;
  sv[tid] = mx*mx;
  __syncthreads();
  for (int st=O>>1; st>0; st>>=1){
    if (o < st) sv[tid] += sv[tid+st];
    __syncthreads();
  }
  if (o == 0) aa[r] = sv[tid];
}

// ================= global kernels =================

#define FPS_SMEM 65664   // 16*8*512 (float4 lp) + 2*8*8 (wred)

// mega1: [fps0 seg (0-3) | knn16 (4..2051) | mlp (2052..4099)] @512thr
__global__ __launch_bounds__(512,2) void mega1(
    const float* __restrict__ xyz, const float* __restrict__ x,
    const float* __restrict__ mlpw, const float* __restrict__ mlpb,
    int* __restrict__ sind0, float* __restrict__ gdmin,
    int* __restrict__ nbr0, float* __restrict__ hA, int M0, int M1)
{
  __shared__ __align__(16) char SMEM[FPS_SMEM];
  int bid = blockIdx.x;
  if (bid < 4){
    fps_mw_seg<8,512,1024>(xyz, 4096, sind0, gdmin, bid, M0, M1, SMEM);
  } else if (bid < 4+2048){
    int kb = bid - 4;
    knn_body<16,512>(xyz, 4096, xyz, nullptr, 4096, nbr0, nullptr, kb>>9, kb&511, 0, SMEM);
  } else {
    int e = (bid - 2052)*512 + threadIdx.x;
    if (e < 4*4096*64){
      int o = e & 63; int r = e >> 6;
      int b = r / 4096; int i = r % 4096;
      const float* xb = x + (size_t)b*3*4096;
      hA[e] = ((mlpw[o*3+0]*xb[i] + mlpw[o*3+1]*xb[4096+i]) + mlpw[o*3+2]*xb[2*4096+i]) + mlpb[o];
    }
  }
}

// [fps0 seg | bngelu-from-part] @512
__global__ __launch_bounds__(512,2) void fps_bngelu(
    const float* fcur, int* sind, float* gdmin, int M0, int M1,
    float* __restrict__ xx, const float* __restrict__ part, float invR, int O, int total)
{
  __shared__ __align__(16) char SMEM[FPS_SMEM];
  if (blockIdx.x < 4){
    fps_mw_seg<8,512,1024>(fcur, 4096, sind, gdmin, blockIdx.x, M0, M1, SMEM);
    return;
  }
  float* mu_s = (float*)SMEM; float* var_s = mu_s + 512;
  for (int oo=threadIdx.x; oo<O; oo+=512){
    float s=0, q=0;
    #pragma unroll 4
    for (int c=0;c<NCHUNK;c++){
      s += part[(size_t)c*1024 + oo];
      q += part[(size_t)(NCHUNK+c)*1024 + oo];
    }
    float mu = s*invR;
    mu_s[oo] = mu;
    var_s[oo] = q*invR - mu*mu;
  }
  __syncthreads();
  int e = (blockIdx.x-4)*512 + threadIdx.x;
  if (e >= total) return;
  int o = e % O;
  float v = (xx[e]-mu_s[o]) / sqrtf(var_s[o] + 1e-5f);
  xx[e] = gelu_f(v);
}

// [fps0 seg | knn8 slice | gemm] @512
template<bool DUAL, bool BN>
__global__ __launch_bounds__(512,2) void fps0_gemm_knn(
    const float* fcur, int* sind, float* gdmin, int M0, int M1,
    const float* cand, int n, const float* qsrc, const int* qidx, int m,
    int* nbrOut, float* outc, int qoff, int NQB, int KNB,
    const float* A, const float* B, float* out0, float* out1,
    int Mg, int Ng, int Kd, int lda, int ldb, int ldo, int boff,
    const float* part, float invR, int nbx)
{
  __shared__ __align__(16) char SMEM[FPS_SMEM];
  if (blockIdx.x < 4){
    fps_mw_seg<8,512,1024>(fcur, 4096, sind, gdmin, blockIdx.x, M0, M1, SMEM);
    return;
  }
  int l = blockIdx.x - 4;
  if (l < KNB){
    knn_body<8,512>(cand, n, qsrc, qidx, m, nbrOut, outc, l/NQB, l%NQB, qoff, SMEM);
    return;
  }
  l -= KNB;
  gemm_body_g<DUAL,BN>(A,B,out0,out1,Mg,Ng,Kd,lda,ldb,ldo,boff,part,invR, l%nbx, l/nbx, SMEM);
}

// [fps0 seg | knn8 slice | gather] @512
__global__ __launch_bounds__(512,2) void fps0_gather_knn(
    const float* fcur, int* sind, float* gdmin, int M0, int M1,
    const float* cand, int n, const float* qsrc, const int* qidx, int m,
    int* nbrOut, float* outc, int qoff, int NQB, int KNB,
    const float* P, const int* nbr, const float* addA, const float* addB,
    float* out, int n_out, int n_src, int O, int K, int total)
{
  __shared__ __align__(16) char SMEM[FPS_SMEM];
  if (blockIdx.x < 4){
    fps_mw_seg<8,512,1024>(fcur, 4096, sind, gdmin, blockIdx.x, M0, M1, SMEM);
    return;
  }
  int l = blockIdx.x - 4;
  if (l < KNB){
    knn_body<8,512>(cand, n, qsrc, qidx, m, nbrOut, outc, l/NQB, l%NQB, qoff, SMEM);
    return;
  }
  int e = (l-KNB)*512 + threadIdx.x;
  gather_elem(P, nbr, addA, addB, out, n_out, n_src, O, K, total, e);
}

// [fps0 seg | knn8 slice | stats_part] @512
__global__ __launch_bounds__(512,2) void fps0_stats_knn(
    const float* fcur, int* sind, float* gdmin, int M0, int M1,
    const float* cand, int n, const float* qsrc, const int* qidx, int m,
    int* nbrOut, float* outc, int qoff, int NQB, int KNB,
    const float* __restrict__ x, int R, int O, float* __restrict__ part)
{
  __shared__ __align__(16) char SMEM[FPS_SMEM];
  if (blockIdx.x < 4){
    fps_mw_seg<8,512,1024>(fcur, 4096, sind, gdmin, blockIdx.x, M0, M1, SMEM);
    return;
  }
  int l = blockIdx.x - 4;
  if (l < KNB){
    knn_body<8,512>(cand, n, qsrc, qidx, m, nbrOut, outc, l/NQB, l%NQB, qoff, SMEM);
    return;
  }
  int o = threadIdx.x;
  if (o >= O) return;
  int chunk = l - KNB;
  int per = (R + NCHUNK - 1)/NCHUNK;
  int r0 = chunk*per, r1 = min(r0+per, R);
  float s=0, q=0;
  for (int r=r0; r<r1; r++){ float v = x[(size_t)r*O + o]; s+=v; q+=v*v; }
  part[(size_t)chunk*1024 + o] = s;
  part[(size_t)(NCHUNK+chunk)*1024 + o] = q;
}

// [knn8 tail q784-1023 (240 blk) | gatherbn SAFE blocks (784: blk%256<196)] @256
__global__ __launch_bounds__(256) void knn_gatherbn_tail(
    const float* cand, int n, const float* qsrc, const int* qidx, int m,
    int* nbrOut, float* outc, int qoff, int NQB, int KNB,
    const float* P, const int* nbr, const float* part, float invR,
    float* out, float* aa, int n_out, int n_src, int O, int K)
{
  __shared__ __align__(16) char SMEM[16384];
  if (blockIdx.x < KNB){
    int l = blockIdx.x;
    knn_body<8,256>(cand, n, qsrc, qidx, m, nbrOut, outc, l/NQB, l%NQB, qoff, SMEM);
    return;
  }
  int l = blockIdx.x - KNB;           // [0,784)
  int blk = (l/196)*256 + (l%196);    // batch-correct safe-row block
  gatherbn_body(P, nbr, part, invR, out, aa, n_out, n_src, O, K, blk, SMEM);
}

// [fps1 seg0 | gatherbn UNSAFE blocks (240: blk%256>=196)] @256
__global__ __launch_bounds__(256) void fps1_gatherbn(
    const float* fcur, int* sind, float* gdmin, int M0, int M1,
    const float* P, const int* nbr, const float* part, float invR,
    float* out, float* aa, int n_out, int n_src, int O, int K)
{
  __shared__ __align__(16) char SMEM[16384];
  if (blockIdx.x < 4){
    if (threadIdx.x < 64) fps_sw_seg<16,256>(fcur, 1024, sind, gdmin, blockIdx.x, M0, M1, SMEM);
    return;
  }
  int l = blockIdx.x - 4;             // [0,240)
  int blk = (l/60)*256 + 196 + (l%60);
  gatherbn_body(P, nbr, part, invR, out, aa, n_out, n_src, O, K, blk, SMEM);
}

// [fps1 seg | symmetric Gram (triangular tiles + mirror)] @256
__global__ __launch_bounds__(256) void fps1_gram(
    const float* fcur, int* sind, float* gdmin, int M0, int M1,
    const float* Ag, float* outg, int Mg, int Kg, long sAg, long sOg, int TPB)
{
  __shared__ __align__(16) char SMEM[16896];
  if (blockIdx.x < 4){
    if (threadIdx.x < 64) fps_sw_seg<16,256>(fcur, 1024, sind, gdmin, blockIdx.x, M0, M1, SMEM);
    return;
  }
  int l = blockIdx.x - 4;
  int bz = l / TPB, t = l % TPB;
  int bx = (int)((sqrtf(8.0f*(float)t + 1.0f) - 1.0f)*0.5f);
  while ((bx+1)*(bx+2)/2 <= t) bx++;
  while (bx*(bx+1)/2 > t) bx--;
  int by = t - bx*(bx+1)/2;
  gram_sym_body(Ag + (size_t)bz*sAg, outg + (size_t)bz*sOg, Mg, Kg, bx, by, SMEM);
}

// [fps1 seg | topk] @256
__global__ __launch_bounds__(256) void fps1_topk(
    const float* fcur, int* sind, float* gdmin, int M0, int M1,
    const float* G, const float* aa, int m, int* nbr)
{
  __shared__ __align__(16) char SMEM[16384];
  if (blockIdx.x < 4){
    if (threadIdx.x < 64) fps_sw_seg<16,256>(fcur, 1024, sind, gdmin, blockIdx.x, M0, M1, SMEM);
    return;
  }
  int l = blockIdx.x - 4;
  int qpb = m/4;
  topk_body<8>(G, aa, m, nbr, l/qpb, l%qpb, SMEM);
}

// combo: [fps_sw | gather] @256
template<int NP, int M>
__global__ __launch_bounds__(256) void fps_gather(
    const float* fcur, int fn, int* sind,
    const float* P, const int* nbr, const float* addA, const float* addB,
    float* out, int n_out, int n_src, int O, int K, int total)
{
  __shared__ __align__(16) char SMEM[(NP*64*16 > 4096) ? NP*64*16 : 4096];
  if (blockIdx.x < 4){
    if (threadIdx.x < 64) fps_sw_body<NP,M>(fcur, fn, sind, blockIdx.x, SMEM);
    return;
  }
  gather_elem(P, nbr, addA, addB, out, n_out, n_src, O, K, total, (blockIdx.x-4)*256 + threadIdx.x);
}

// combo: [knn8 | gemm] @256, template DUAL/BN
template<bool DUAL, bool BN>
__global__ __launch_bounds__(256) void knn_gemm2(
    const float* cand, int n, const float* qsrc, const int* qidx, int m,
    int* nbrOut, float* outc, int KNB,
    const float* A, const float* B, float* out0, float* out1,
    int Mg, int Ng, int Kd, int boff,
    const float* part, float invR, int nbx)
{
  __shared__ __align__(16) char SMEM[16896];
  if (blockIdx.x < KNB){
    int qpb = m/4;
    knn_body<8,256>(cand, n, qsrc, qidx, m, nbrOut, outc, blockIdx.x/qpb, blockIdx.x%qpb, 0, SMEM);
    return;
  }
  int l = blockIdx.x - KNB;
  gemm_body<DUAL,BN>(A,B,out0,out1,Mg,Ng,Kd,Kd,DUAL?2*Kd:Kd,Ng,boff,0,0,0,part,invR, l%nbx, l/nbx, 0, SMEM);
}

// combo: [knn8 | gatherbn] @256
__global__ __launch_bounds__(256) void knn_gatherbn(
    const float* cand, int n, const float* qsrc, const int* qidx, int m,
    int* nbrOut, int KNB,
    const float* P, const int* nbr, const float* part, float invR,
    float* out, float* aa, int n_out, int n_src, int O, int K)
{
  __shared__ __align__(16) char SMEM[16384];
  if (blockIdx.x < KNB){
    int qpb = m/4;
    knn_body<8,256>(cand, n, qsrc, qidx, m, nbrOut, nullptr, blockIdx.x/qpb, blockIdx.x%qpb, 0, SMEM);
    return;
  }
  gatherbn_body(P, nbr, part, invR, out, aa, n_out, n_src, O, K, blockIdx.x-KNB, SMEM);
}

// combo: [Gram | gemm1 (DUAL)] @256
__global__ __launch_bounds__(256) void gram_gemm(
    const float* Ag, float* outg, int Mg, int Kg, long sAg, long sOg,
    int ngx, int ngy, int NG,
    const float* A2, const float* B2, float* o20, float* o21,
    int M2, int N2, int K2, int boff2, int nb2x)
{
  __shared__ __align__(16) char SMEM[16896];
  int l = blockIdx.x;
  if (l < NG){
    int bx = l % ngx, by = (l/ngx) % ngy, bz = l/(ngx*ngy);
    gemm_body<false,false>(Ag,Ag,outg,nullptr,Mg,Mg,Kg,Kg,Kg,Mg,0,sAg,sAg,sOg,nullptr,0.f,bx,by,bz,SMEM);
    return;
  }
  l -= NG;
  gemm_body<true,false>(A2,B2,o20,o21,M2,N2,K2,K2,2*K2,N2,boff2,0,0,0,nullptr,0.f, l%nb2x, l/nb2x, 0, SMEM);
}

// fused gemm2(BN) + shortcut-gemm
__global__ __launch_bounds__(256) void gemm2sc(
    const float* A2, const float* B2, float* o20, float* o21, int R, int O2, int O1v,
    const float* part, float invR,
    const float* Asc, const float* Bsc, float* osc, int Cin,
    int nbx, int nby)
{
  __shared__ __align__(16) char SMEM[16896];
  int l = blockIdx.x;
  int half = nbx*nby;
  if (l < half){
    gemm_body<true,true>(A2,B2,o20,o21,R,O2,O1v,O1v,2*O1v,O2,O1v,0,0,0,part,invR, l%nbx, l/nbx, 0, SMEM);
  } else {
    l -= half;
    gemm_body<false,false>(Asc,Bsc,osc,nullptr,R,O2,Cin,Cin,Cin,O2,0,0,0,0,nullptr,0.f, l%nbx, l/nbx, 0, SMEM);
  }
}

__global__ __launch_bounds__(256) void gathermax_kernel(
    const float* P, const int* nbr, const float* addA, const float* addB,
    float* out, int n_out, int n_src, int O, int K, int total)
{
  gather_elem(P, nbr, addA, addB, out, n_out, n_src, O, K, total, blockIdx.x*256 + threadIdx.x);
}

__global__ __launch_bounds__(256) void gatherbn_kernel(
    const float* P, const int* nbr, const float* part, float invR,
    float* out, float* aa, int n_out, int n_src, int O, int K)
{
  __shared__ __align__(16) char SMEM[3072];
  gatherbn_body(P, nbr, part, invR, out, aa, n_out, n_src, O, K, blockIdx.x, SMEM);
}

// standalone top-K
template<int K>
__global__ __launch_bounds__(256) void topk_wave(
    const float* __restrict__ G, const float* __restrict__ aa, int m,
    int* __restrict__ nbr)
{
  __shared__ __align__(16) char SMEM[4096];
  topk_body<K>(G, aa, m, nbr, blockIdx.y, blockIdx.x, SMEM);
}

__global__ void stats_part_kernel(const float* __restrict__ x, int R, int O,
                                  float* __restrict__ part)
{
  int o = threadIdx.x;
  int chunk = blockIdx.x;
  int per = (R + NCHUNK - 1)/NCHUNK;
  int r0 = chunk*per, r1 = min(r0+per, R);
  float s=0, q=0;
  for (int r=r0; r<r1; r++){ float v = x[(size_t)r*O + o]; s+=v; q+=v*v; }
  part[(size_t)chunk*1024 + o] = s;
  part[(size_t)(NCHUNK+chunk)*1024 + o] = q;
}

// head with BN+gelu folded on load
__global__ __launch_bounds__(1024) void head_kernel(const float* __restrict__ h,
    const float* __restrict__ part, float invR,
    const float* __restrict__ w1, const float* __restrict__ w2,
    const float* __restrict__ b2, float* __restrict__ out)
{
  __shared__ __align__(16) float mu_s[512], var_s[512];
  __shared__ __align__(16) float g[4*512];
  __shared__ __align__(16) float t[4*256];
  int tid = threadIdx.x;
  for (int oo=tid; oo<512; oo+=1024){
    float s=0, q=0;
    #pragma unroll 4
    for (int c=0;c<NCHUNK;c++){
      s += part[(size_t)c*1024 + oo];
      q += part[(size_t)(NCHUNK+c)*1024 + oo];
    }
    float mu = s*invR;
    mu_s[oo] = mu;
    var_s[oo] = q*invR - mu*mu;
  }
  __syncthreads();
  for (int e=tid; e<2048; e+=1024){
    int b=e>>9, c=e&511;
    float mu = mu_s[c], sd = sqrtf(var_s[c] + 1e-5f);
    float s=0;
    for (int p=0;p<16;p++){
      float v = h[((size_t)(b*16+p))*512 + c];
      s += gelu_f((v-mu)/sd);
    }
    g[e] = s * (1.0f/16.0f);
  }
  __syncthreads();
  {
    int b = tid>>8, j = tid&255;
    const float4* gr = (const float4*)(g + b*512);
    const float4* wr = (const float4*)(w1 + (size_t)j*512);
    float s=0;
    for (int c=0;c<128;c++){
      float4 a=gr[c], w=wr[c];
      s = fmaf(a.x,w.x, fmaf(a.y,w.y, fmaf(a.z,w.z, fmaf(a.w,w.w, s))));
    }
    t[tid] = s;
  }
  __syncthreads();
  if (tid < 256){
    float v0=t[tid], v1=t[256+tid], v2=t[512+tid], v3=t[768+tid];
    float mu = ((v0+v1)+v2+v3)*0.25f;
    float d0=v0-mu, d1=v1-mu, d2=v2-mu, d3=v3-mu;
    float var = ((d0*d0+d1*d1)+d2*d2+d3*d3)*0.25f;
    float sq = sqrtf(var + 1e-5f);
    t[tid]     = gelu_f(d0/sq);
    t[256+tid] = gelu_f(d1/sq);
    t[512+tid] = gelu_f(d2/sq);
    t[768+tid] = gelu_f(d3/sq);
  }
  __syncthreads();
  if (tid < 160){
    int b = tid/40, o = tid%40;
    const float* tr = t + b*256; const float* wr = w2 + (size_t)o*256;
    float s=0;
    for (int j=0;j<256;j++) s = fmaf(tr[j], wr[j], s);
    out[tid] = s + b2[o];
  }
}

// =====================================================================
extern "C" void kernel_launch(void* const* d_in, const int* in_sizes, int n_in,
                              void* d_out, int out_size, void* d_ws, size_t ws_size,
                              hipStream_t stream)
{
  const float* x    = (const float*)d_in[0];
  const float* xyz  = (const float*)d_in[1];
  const float* mlpw = (const float*)d_in[2];
  const float* mlpb = (const float*)d_in[3];
  const float* c0l1 = (const float*)d_in[4];
  const float* c0l2 = (const float*)d_in[5];
  const float* L1[4] = {(const float*)d_in[6], (const float*)d_in[8],
                        (const float*)d_in[11], (const float*)d_in[14]};
  const float* L2[4] = {(const float*)d_in[7], (const float*)d_in[9],
                        (const float*)d_in[12], (const float*)d_in[15]};
  const float* SC[4] = {nullptr, (const float*)d_in[10],
                        (const float*)d_in[13], (const float*)d_in[16]};
  const float* hw1 = (const float*)d_in[17];
  const float* hw2 = (const float*)d_in[18];
  const float* hb2 = (const float*)d_in[19];
  float* out = (float*)d_out;

  float* ws = (float*)d_ws;
  const size_t MF = 1024*1024;
  float* D    = ws;               // 4M floats (Gram)
  float* hA   = ws + 4*MF;
  float* hX   = ws + 5*MF;
  float* hP   = ws + 6*MF;
  float* hCT  = ws + 7*MF;
  float* hSH  = ws + 8*MF;
  float* hH1  = ws + 9*MF;
  float* hOUT = ws + 10*MF;
  float* aux  = ws + 11*MF;
  int*   nbr0  = (int*)aux;                 aux += 262144;
  int*   nbrS0 = (int*)aux;                 aux += 32768;
  int*   nbrS1 = (int*)aux;                 aux += 8192;
  int*   nbrS2 = (int*)aux;                 aux += 2048;
  int*   nbrS3 = (int*)aux;                 aux += 512;
  int*   nbrF  = (int*)aux;                 aux += 32768;
  int*   sind0 = (int*)aux;                 aux += 4096;
  int*   sind1 = (int*)aux;                 aux += 1024;
  int*   sind2 = (int*)aux;                 aux += 256;
  int*   sind3 = (int*)aux;                 aux += 64;
  float* aa    = aux;                       aux += 4096;
  float* cur1  = aux;                       aux += 12288;
  float* cur2  = aux;                       aux += 3072;
  float* cur3  = aux;                       aux += 768;
  float* part  = aux;                       aux += 65536;
  float* gdmin = aux;                       aux += 16384;

  int tot0 = 4*4096*64;

  // ---- fps0 windows with ec0 chain + query-sliced knn8 riding along (R19 budgets) ----
  // W1: fps 0-300 | knn16 | mlp
  mega1<<<4100, 512, 0, stream>>>(xyz, x, mlpw, mlpb, sind0, gdmin, nbr0, hA, 0, 300);
  stats_part_kernel<<<NCHUNK, 64, 0, stream>>>(hA, 16384, 64, part);
  // W2: fps 300-345 | bngelu(hA)
  fps_bngelu<<<4+2048, 512, 0, stream>>>(xyz, sind0, gdmin, 300, 345, hA, part, 1.0f/16384.0f, 64, tot0);
  // W3: fps 345-470 | knn8 q0-255 | ec0 gemm1
  fps0_gemm_knn<true,false><<<4+128+256, 512, 0, stream>>>(xyz, sind0, gdmin, 345, 470,
      xyz, 4096, xyz, sind0, 1024, nbrS0, cur1, 0, 32, 128,
      hA, c0l1, hP, hCT, 16384, 64, 64, 64, 128, 64, 64, nullptr, 0.f, 1);
  // W4: fps 470-645 | knn8 q256-463 | ec0 gather1
  fps0_gather_knn<<<4+104+2048, 512, 0, stream>>>(xyz, sind0, gdmin, 470, 645,
      xyz, 4096, xyz, sind0, 1024, nbrS0, cur1, 256, 26, 104,
      hP, nbr0, hCT, nullptr, hH1, 4096, 4096, 64, 16, 1048576);
  stats_part_kernel<<<NCHUNK, 64, 0, stream>>>(hH1, 16384, 64, part);
  // W5: fps 645-720 | knn8 q464-639 | ec0 gemm2 (BN)
  fps0_gemm_knn<true,true><<<4+88+256, 512, 0, stream>>>(xyz, sind0, gdmin, 645, 720,
      xyz, 4096, xyz, sind0, 1024, nbrS0, cur1, 464, 22, 88,
      hH1, c0l2, hP, hCT, 16384, 64, 64, 64, 128, 64, 64, part, 1.0f/16384.0f, 1);
  // W6: fps 720-820 | knn8 q640-687 | ec0 gather2 (+hA residual)
  fps0_gather_knn<<<4+24+2048, 512, 0, stream>>>(xyz, sind0, gdmin, 720, 820,
      xyz, 4096, xyz, sind0, 1024, nbrS0, cur1, 640, 6, 24,
      hP, nbr0, hCT, hA, hOUT, 4096, 4096, 64, 16, 1048576);
  // W7: fps 820-1024 | knn8 q688-783 | stats(hOUT)
  fps0_stats_knn<<<4+48+NCHUNK, 512, 0, stream>>>(xyz, sind0, gdmin, 820, 1024,
      xyz, 4096, xyz, sind0, 1024, nbrS0, cur1, 688, 12, 48,
      hOUT, 16384, 64, part);
  // fps0 complete; hOUT = ec0 output (raw) + stats in part

  // ---- stage0 pre ----
  // Tail: [knn8 q784-1023 (240 blk) | gatherbn SAFE rows (784 blk, i<784 per batch)]
  knn_gatherbn_tail<<<240+784, 256, 0, stream>>>(
      xyz, 4096, xyz, sind0, 1024, nbrS0, cur1, 784, 60, 240,
      hOUT, nbrS0, part, 1.0f/16384.0f, hX, aa, 1024, 4096, 64, 8);
  // [fps1 seg0 0-86 | gatherbn UNSAFE rows (240 blk, i>=784)]
  fps1_gatherbn<<<4+240, 256, 0, stream>>>(cur1, sind1, gdmin, 0, 86,
      hOUT, nbrS0, part, 1.0f/16384.0f, hX, aa, 1024, 4096, 64, 8);
  // [fps1 seg1 86-171 | Gram0 symmetric: 136 triangular tiles x 4 batches]
  fps1_gram<<<4+544, 256, 0, stream>>>(cur1, sind1, gdmin, 86, 171,
      hX, D, 1024, 64, (long)1024*64, (long)1024*1024, 136);
  // [fps1 seg2 171-256 | topk m=1024]
  fps1_topk<<<4+1024, 256, 0, stream>>>(cur1, sind1, gdmin, 171, 256,
      D, aa, 1024, nbrF);
  // [knn8_1 (m=256 vs cur1; needs full sind1) | s0 gemm1]
  knn_gemm2<true,false><<<256+64,256,0,stream>>>(cur1, 1024, cur1, sind1, 256,
      nbrS1, cur2, 256,
      hX, L1[0], hP, hCT, 4096, 64, 64, 64, nullptr, 0.f, 1);
  // [fps2 (cur2, 256->64) | s0 gather1]
  fps_gather<4,64><<<4+1024,256,0,stream>>>(cur2, 256, sind2,
      hP, nbrF, hCT, nullptr, hH1, 1024, 1024, 64, 8, 262144);
  stats_part_kernel<<<NCHUNK, 64, 0, stream>>>(hH1, 4096, 64, part);
  // [knn8_2 (m=64 vs cur2) | s0 gemm2 BN]
  knn_gemm2<true,true><<<64+64,256,0,stream>>>(cur2, 256, cur2, sind2, 64,
      nbrS2, cur3, 64,
      hH1, L2[0], hP, hCT, 4096, 64, 64, 64, part, 1.0f/4096.0f, 1);
  // [fps3 (cur3, 64->16) | s0 gather2 (+hX residual)]
  fps_gather<1,16><<<4+1024,256,0,stream>>>(cur3, 64, sind3,
      hP, nbrF, hCT, hX, hA, 1024, 1024, 64, 8, 262144);
  stats_part_kernel<<<NCHUNK, 64, 0, stream>>>(hA, 4096, 64, part);
  // [knn8_3 (m=16 vs cur3) | stage1 gatherbn hA->hX + aa]
  knn_gatherbn<<<16+256,256,0,stream>>>(cur3, 64, cur3, sind3, 16,
      nbrS3, 16,
      hA, nbrS1, part, 1.0f/4096.0f, hX, aa, 256, 1024, 64, 8);
  // hX = stage1 downsampled input (post-BN), aa = norms

  // ---- stages 1-3 (geometry precomputed) ----
  const int   mArr[3]   = {256, 64, 16};
  const int   nsrcArr[3]= {1024, 256, 64};
  const int   CinArr[3] = {64, 128, 256};
  const int   OArr[3]   = {128, 256, 512};
  const int*  nbrSs[3]  = {nbrS1, nbrS2, nbrS3};
  float* hcur = hA;
  float invRprev = 1.0f/4096.0f;
  for (int s=0;s<3;s++){
    int m = mArr[s], nsrc = nsrcArr[s], Cin = CinArr[s], O1 = OArr[s], O2 = OArr[s];
    int R = 4*m;
    int th = R*Cin;
    if (s > 0){
      gatherbn_kernel<<<th/256,256,0,stream>>>(hcur, nbrSs[s], part, invRprev,
                                               hX, aa, m, nsrc, Cin, 8);
    }
    int ngx = (m+63)/64, ngy = (m+63)/64;
    int NG = ngx*ngy*4;
    int nb1x = (O1+63)/64, nb1y = (R+63)/64;
    gram_gemm<<<NG + nb1x*nb1y, 256, 0, stream>>>(
        hX, D, m, Cin, (long)m*Cin, (long)m*m, ngx, ngy, NG,
        hX, L1[s+1], hP, hCT, R, O1, Cin, Cin, nb1x);
    topk_wave<8><<<dim3(m/4,4),256,0,stream>>>(D, aa, m, nbrF);
    int t1 = R*O1;
    gathermax_kernel<<<(t1+255)/256,256,0,stream>>>(hP, nbrF, hCT, nullptr, hH1, m, m, O1, 8, t1);
    stats_part_kernel<<<NCHUNK, O1, 0, stream>>>(hH1, R, O1, part);
    int nbx = (O2+63)/64, nby = (R+63)/64;
    gemm2sc<<<2*nbx*nby,256,0,stream>>>(hH1, L2[s+1], hP, hCT, R, O2, O1, part, 1.0f/R,
                                        hX, SC[s+1], hSH, Cin, nbx, nby);
    int t2 = R*O2;
    float* outbuf = (s&1) ? hA : hOUT;
    gathermax_kernel<<<(t2+255)/256,256,0,stream>>>(hP, nbrF, hCT, hSH, outbuf, m, m, O2, 8, t2);
    stats_part_kernel<<<NCHUNK, O2, 0, stream>>>(outbuf, R, O2, part);
    hcur = outbuf;
    invRprev = 1.0f/R;
  }

  head_kernel<<<1,1024,0,stream>>>(hcur, part, 1.0f/64.0f, hw1, hw2, hb2, out);
}

// Round 22
// 1475.514 us; speedup vs baseline: 1.0417x; 1.0152x over previous
//
#include <hip/hip_runtime.h>
#include <math.h>

#define NCHUNK 32
typedef unsigned long long ull;

__device__ __forceinline__ float gelu_f(float v){
  return 0.5f*v*(1.0f+erff(v*0.70710678118654752440f));
}

__device__ __forceinline__ unsigned flipf(float d){
  unsigned u = __float_as_uint(d);
  return (u & 0x80000000u) ? ~u : (u | 0x80000000u);
}

// ---- DPP helpers ----
template<int CTRL>
__device__ __forceinline__ ull dpp64(ull k){
  int lo = __builtin_amdgcn_update_dpp(0, (int)(unsigned)k,       CTRL, 0xF, 0xF, true);
  int hi = __builtin_amdgcn_update_dpp(0, (int)(unsigned)(k>>32), CTRL, 0xF, 0xF, true);
  return ((ull)(unsigned)hi<<32) | (unsigned)lo;
}
__device__ __forceinline__ ull rl64(ull k, int l){
  unsigned lo = (unsigned)__builtin_amdgcn_readlane((int)(unsigned)k, l);
  unsigned hi = (unsigned)__builtin_amdgcn_readlane((int)(unsigned)(k>>32), l);
  return ((ull)hi<<32) | lo;
}
// FPS keys: hi = float bits of nd>=0 -> u64 order == f64 order (positive doubles).
__device__ __forceinline__ ull fmax64(ull a, ull b){
  return (ull)__double_as_longlong(fmax(__longlong_as_double((long long)a),
                                        __longlong_as_double((long long)b)));
}
__device__ __forceinline__ ull wave_fmax(ull k){
  k = fmax64(k, dpp64<0xB1>(k));
  k = fmax64(k, dpp64<0x4E>(k));
  k = fmax64(k, dpp64<0x141>(k));
  k = fmax64(k, dpp64<0x140>(k));
  ull a=rl64(k,0), b=rl64(k,16), c=rl64(k,32), d=rl64(k,48);
  return fmax64(fmax64(a,b), fmax64(c,d));
}
// kNN keys are positive doubles (flip*4096+j) -> f64 min directly.
template<int CTRL>
__device__ __forceinline__ double dmin_dpp(double k){
  ull o = dpp64<CTRL>((ull)__double_as_longlong(k));
  return fmin(k, __longlong_as_double((long long)o));
}
__device__ __forceinline__ double wave_dmin(double k){
  k = dmin_dpp<0xB1>(k);
  k = dmin_dpp<0x4E>(k);
  k = dmin_dpp<0x141>(k);
  k = dmin_dpp<0x140>(k);
  ull kb = (ull)__double_as_longlong(k);
  double a = __longlong_as_double((long long)rl64(kb,0));
  double b = __longlong_as_double((long long)rl64(kb,16));
  double c = __longlong_as_double((long long)rl64(kb,32));
  double d = __longlong_as_double((long long)rl64(kb,48));
  return fmin(fmin(a,b), fmin(c,d));
}

// ================= device bodies =================

// ---- wave-per-query kNN; key = flip(d)*4096 + j (exact f64, lex order) ----
template<int K, int T>
__device__ __forceinline__ void knn_body(
    const float* __restrict__ cand, int n,
    const float* __restrict__ qsrc, const int* __restrict__ qidx, int m,
    int* __restrict__ nbr, float* __restrict__ outc,
    int b, int qblk, int qoff, char* smem)
{
  float4* tile = (float4*)smem;   // 1024 entries, 16KB
  constexpr int NWV = T/64;
  int wv = threadIdx.x >> 6, lane = threadIdx.x & 63;
  int q = qblk*NWV + wv + qoff;
  const float* cb = cand + (size_t)b*3*n;
  int qi = qidx ? qidx[(size_t)b*m + q] : q;
  const float* qb = qsrc + (size_t)b*3*n;
  float qx = qb[qi], qy = qb[n+qi], qz = qb[2*n+qi];
  float aa = (qx*qx + qy*qy) + qz*qz;

  double a[K];
  #pragma unroll
  for (int k=0;k<K;k++) a[k] = 1e300;

  for (int base=0; base<n; base+=1024){
    int cnt = min(1024, n-base);
    for (int j=threadIdx.x; j<cnt; j+=T){
      float x=cb[base+j], y=cb[n+base+j], z=cb[2*n+base+j];
      tile[j] = make_float4(x,y,z,(x*x+y*y)+z*z);
    }
    __syncthreads();
    int steps = cnt >> 6;
    double jd = (double)(base + lane);
    for (int i=0;i<steps;i++){
      int j = lane + (i<<6);
      float4 c = tile[j];
      float d = aa + c.w - 2.0f*((qx*c.x+qy*c.y)+qz*c.z);
      double key = (double)flipf(d) * 4096.0 + jd;
      if (key < a[K-1]){
        #pragma unroll
        for (int k=K-1;k>=1;k--)
          a[k] = fmin(fmax(a[k-1], key), a[k]);
        a[0] = fmin(a[0], key);
      }
      jd += 64.0;
    }
    __syncthreads();
  }

  double head = a[0];
  int res[K];
  #pragma unroll
  for (int r=0; r<K; r++){
    double mk = wave_dmin(head);
    res[r] = (int)((ull)mk & 4095u);
    if (head == mk){
      #pragma unroll
      for (int i2=0;i2<K-1;i2++) a[i2]=a[i2+1];
      a[K-1] = 1e300;
      head = a[0];
    }
  }
  if (lane == 0){
    int* o = nbr + ((size_t)b*m + q)*K;
    #pragma unroll
    for (int r=0;r<K;r++) o[r] = res[r];
  }
  if (outc != nullptr && lane < 3){
    const float* cd = cb + (size_t)lane*n;
    float s=0;
    #pragma unroll
    for (int k=0;k<K;k++) s += cd[res[k]];
    outc[((size_t)b*3 + lane)*m + q] = s * (1.0f/K);
  }
}

// ---- top-K from Gram rows (f64 keys) body ----
template<int K>
__device__ __forceinline__ void topk_body(
    const float* __restrict__ G, const float* __restrict__ aa, int m,
    int* __restrict__ nbr, int b, int qblk, char* smem)
{
  float* abs_s = (float*)smem;
  int wv = threadIdx.x >> 6, lane = threadIdx.x & 63;
  int q = qblk*4 + wv;
  const float* ab = aa + (size_t)b*m;
  for (int j=threadIdx.x; j<m; j+=256) abs_s[j] = ab[j];
  __syncthreads();
  float aq = ab[q];
  const float* Gq = G + ((size_t)b*m + q)*m;

  double a[K];
  #pragma unroll
  for (int k=0;k<K;k++) a[k] = 1e300;

  int steps = (m+63)>>6;
  double jd = (double)lane;
  for (int i=0;i<steps;i++){
    int j = lane + (i<<6);
    double key = 1e300;
    if (j < m){
      float g = Gq[j];
      float d = aq + abs_s[j] - 2.0f*g;
      key = (double)flipf(d) * 4096.0 + jd;
    }
    if (key < a[K-1]){
      #pragma unroll
      for (int k=K-1;k>=1;k--)
        a[k] = fmin(fmax(a[k-1], key), a[k]);
      a[0] = fmin(a[0], key);
    }
    jd += 64.0;
  }
  double head = a[0];
  int res[K];
  #pragma unroll
  for (int r=0; r<K; r++){
    double mk = wave_dmin(head);
    res[r] = (int)((ull)mk & 4095u);
    if (head == mk){
      #pragma unroll
      for (int i2=0;i2<K-1;i2++) a[i2]=a[i2+1];
      a[K-1] = 1e300;
      head = a[0];
    }
  }
  if (lane == 0){
    int* o = nbr + ((size_t)b*m + q)*K;
    #pragma unroll
    for (int r=0;r<K;r++) o[r] = res[r];
  }
}

// ---- segmented multi-wave FPS (generic wave count) ----
template<int NP, int T, int M>
__device__ __forceinline__ void fps_mw_seg(const float* __restrict__ cur, int n,
                                           int* __restrict__ sind, float* __restrict__ gdmin,
                                           int b, int M0, int M1, char* smem)
{
  constexpr int NW = T/64;
  int tid = threadIdx.x;
  int wv = tid>>6;
  const float* cb = cur + (size_t)b*3*n;
  float4* lp = (float4*)smem;
  ull* wred = (ull*)(smem + sizeof(float4)*NP*T);
  float* gd = gdmin + (size_t)b*n;
  float px[NP], py[NP], pz[NP], dmin[NP];
  unsigned nj[NP];
  #pragma unroll
  for (int s=0;s<NP;s++){
    int j = tid + s*T;
    px[s]=cb[j]; py[s]=cb[n+j]; pz[s]=cb[2*n+j];
    dmin[s] = (M0==0) ? 1e30f : gd[j];
    nj[s] = (unsigned)(~j);
    lp[j] = make_float4(px[s],py[s],pz[s],0.f);
  }
  __syncthreads();
  int ci = (M0==0) ? 0 : sind[(size_t)b*M + (M0-1)];
  float4 w0 = lp[ci];
  float X = w0.x, Y = w0.y, Z = w0.z;
  if (M0==0 && tid==0) sind[(size_t)b*M] = 0;
  __builtin_amdgcn_s_setprio(3);
  int p = 0;
  int s0 = (M0==0) ? 1 : M0;
  for (int step=s0; step<M1; step++){
    ull key[NP];
    #pragma unroll
    for (int s=0;s<NP;s++){
      float dx=px[s]-X, dy=py[s]-Y, dz=pz[s]-Z;
      float d = (dx*dx + dy*dy) + dz*dz;
      float nd = fminf(dmin[s], d);
      dmin[s] = nd;
      key[s] = ((ull)__float_as_uint(nd)<<32) | nj[s];
    }
    #pragma unroll
    for (int w=NP; w>1; w>>=1)
      #pragma unroll
      for (int i=0;i<NP;i++) if (i < (w>>1))
        key[i] = fmax64(key[i], key[i+(w>>1)]);
    ull wk = wave_fmax(key[0]);
    if ((tid&63)==0) wred[p*NW + wv] = wk;
    __syncthreads();
    ull gk;
    if (NW == 8){
      const ulonglong2* wp2 = (const ulonglong2*)(wred + p*NW);
      ulonglong2 m0 = wp2[0], m1 = wp2[1], m2 = wp2[2], m3 = wp2[3];
      gk = fmax64(fmax64(fmax64(m0.x,m0.y), fmax64(m1.x,m1.y)),
                  fmax64(fmax64(m2.x,m2.y), fmax64(m3.x,m3.y)));
    } else {
      gk = wred[p*NW];
      #pragma unroll
      for (int i=1;i<NW;i++) gk = fmax64(gk, wred[p*NW+i]);
    }
    int gi = (int)(~(unsigned)gk);
    if (tid==0) sind[(size_t)b*M + step] = gi;
    float4 wp = lp[gi];
    X=wp.x; Y=wp.y; Z=wp.z;
    p ^= 1;
  }
  __builtin_amdgcn_s_setprio(0);
  #pragma unroll
  for (int s=0;s<NP;s++) gd[tid + s*T] = dmin[s];
}

// ---- single-wave FPS (non-segmented) ----
template<int NP, int M>
__device__ __forceinline__ void fps_sw_body(const float* __restrict__ cur, int n,
                                            int* __restrict__ sind, int b, char* smem)
{
  int lane = threadIdx.x;
  const float* cb = cur + (size_t)b*3*n;
  float4* lp = (float4*)smem;
  float px[NP], py[NP], pz[NP], dmin[NP];
  unsigned nj[NP];
  #pragma unroll
  for (int s=0;s<NP;s++){
    int j = lane + s*64;
    px[s]=cb[j]; py[s]=cb[n+j]; pz[s]=cb[2*n+j]; dmin[s]=1e30f;
    nj[s] = (unsigned)(~j);
    lp[j] = make_float4(px[s],py[s],pz[s],0.f);
  }
  float X = lp[0].x, Y = lp[0].y, Z = lp[0].z;
  if (lane==0) sind[(size_t)b*M] = 0;
  __builtin_amdgcn_s_setprio(3);
  for (int step=1; step<M; step++){
    ull key[NP];
    #pragma unroll
    for (int s=0;s<NP;s++){
      float dx=px[s]-X, dy=py[s]-Y, dz=pz[s]-Z;
      float d = (dx*dx + dy*dy) + dz*dz;
      float nd = fminf(dmin[s], d);
      dmin[s] = nd;
      key[s] = ((ull)__float_as_uint(nd)<<32) | nj[s];
    }
    #pragma unroll
    for (int w=NP; w>1; w>>=1)
      #pragma unroll
      for (int i=0;i<NP;i++) if (i < (w>>1))
        key[i] = fmax64(key[i], key[i+(w>>1)]);
    ull gk = wave_fmax(key[0]);
    int gi = (int)(~(unsigned)gk);
    if (lane==0) sind[(size_t)b*M + step] = gi;
    float4 wp = lp[gi];
    X=wp.x; Y=wp.y; Z=wp.z;
  }
  __builtin_amdgcn_s_setprio(0);
}

// ---- tiled NT GEMM body; BN variant finalizes mu/var from `part` in LDS ----
template<bool DUAL, bool BN>
__device__ __forceinline__ void gemm_body(
    const float* __restrict__ A, const float* __restrict__ B,
    float* __restrict__ out0, float* __restrict__ out1,
    int M, int N, int Kd, int lda, int ldb, int ldo, int boff,
    long sA, long sB, long sO, const float* __restrict__ part, float invR,
    int bxi, int byi, int bzi, char* smem)
{
  A += (size_t)bzi * sA; B += (size_t)bzi * sB;
  float* o0 = out0 + (size_t)bzi * sO;
  float* o1 = DUAL ? (out1 + (size_t)bzi * sO) : nullptr;
  int rowBase = byi*64, colBase = bxi*64;
  float (*As)[64]  = (float(*)[64])smem;
  float (*Bs0)[64] = (float(*)[64])(smem + 4096);
  float (*Bs1)[64] = (float(*)[64])(smem + 8192);
  float* mu_s = (float*)(smem + 12288);
  float* var_s = mu_s + 512;
  int tid = threadIdx.x;
  if (BN){
    for (int oo=tid; oo<Kd; oo+=blockDim.x){
      float s=0, q=0;
      #pragma unroll 4
      for (int c=0;c<NCHUNK;c++){
        s += part[(size_t)c*1024 + oo];
        q += part[(size_t)(NCHUNK+c)*1024 + oo];
      }
      float mu = s*invR;
      mu_s[oo] = mu;
      var_s[oo] = q*invR - mu*mu;
    }
    __syncthreads();
  }
  int ty = tid>>4, tx = tid&15;
  float acc0[4][4] = {}, acc1[4][4] = {};
  int lr = tid>>2, lk = (tid&3)*4;
  for (int k0=0; k0<Kd; k0+=16) {
    float4 va = make_float4(0,0,0,0);
    int r = rowBase + lr;
    if (r < M) va = *(const float4*)(A + (size_t)r*lda + k0 + lk);
    if (BN){
      int c = k0 + lk;
      va.x = gelu_f((va.x - mu_s[c+0]) / sqrtf(var_s[c+0] + 1e-5f));
      va.y = gelu_f((va.y - mu_s[c+1]) / sqrtf(var_s[c+1] + 1e-5f));
      va.z = gelu_f((va.z - mu_s[c+2]) / sqrtf(var_s[c+2] + 1e-5f));
      va.w = gelu_f((va.w - mu_s[c+3]) / sqrtf(var_s[c+3] + 1e-5f));
    }
    As[lk+0][lr]=va.x; As[lk+1][lr]=va.y; As[lk+2][lr]=va.z; As[lk+3][lr]=va.w;
    float4 vb = make_float4(0,0,0,0), vb2 = make_float4(0,0,0,0);
    int c2 = colBase + lr;
    if (c2 < N) {
      vb = *(const float4*)(B + (size_t)c2*ldb + k0 + lk);
      if (DUAL) vb2 = *(const float4*)(B + (size_t)c2*ldb + boff + k0 + lk);
    }
    Bs0[lk+0][lr]=vb.x; Bs0[lk+1][lr]=vb.y; Bs0[lk+2][lr]=vb.z; Bs0[lk+3][lr]=vb.w;
    if (DUAL) {
      Bs1[lk+0][lr]=vb2.x-vb.x; Bs1[lk+1][lr]=vb2.y-vb.y;
      Bs1[lk+2][lr]=vb2.z-vb.z; Bs1[lk+3][lr]=vb2.w-vb.w;
    }
    __syncthreads();
    #pragma unroll
    for (int kk=0;kk<16;kk++){
      float4 a  = *(const float4*)&As[kk][ty*4];
      float4 b0 = *(const float4*)&Bs0[kk][tx*4];
      float av[4]={a.x,a.y,a.z,a.w};
      float b0v[4]={b0.x,b0.y,b0.z,b0.w};
      #pragma unroll
      for (int i=0;i<4;i++)
        #pragma unroll
        for (int j=0;j<4;j++) acc0[i][j] = fmaf(av[i], b0v[j], acc0[i][j]);
      if (DUAL) {
        float4 b1 = *(const float4*)&Bs1[kk][tx*4];
        float b1v[4]={b1.x,b1.y,b1.z,b1.w};
        #pragma unroll
        for (int i=0;i<4;i++)
          #pragma unroll
          for (int j=0;j<4;j++) acc1[i][j] = fmaf(av[i], b1v[j], acc1[i][j]);
      }
    }
    __syncthreads();
  }
  #pragma unroll
  for (int i=0;i<4;i++){
    int r = rowBase + ty*4 + i;
    if (r < M) {
      #pragma unroll
      for (int j=0;j<4;j++){
        int c = colBase + tx*4 + j;
        if (c < N) {
          o0[(size_t)r*ldo + c] = acc0[i][j];
          if (DUAL) o1[(size_t)r*ldo + c] = acc1[i][j];
        }
      }
    }
  }
}

// ---- symmetric Gram tile body (A·Aᵀ) ----
__device__ __forceinline__ void gram_sym_body(
    const float* __restrict__ A, float* __restrict__ o0,
    int M, int Kd, int bxi, int byi, char* smem)
{
  int rowBase = byi*64, colBase = bxi*64;
  float (*As)[64] = (float(*)[64])smem;
  float (*Bs)[64] = (float(*)[64])(smem + 4096);
  int tid = threadIdx.x;
  int ty = tid>>4, tx = tid&15;
  float acc[4][4] = {};
  int lr = tid>>2, lk = (tid&3)*4;
  for (int k0=0; k0<Kd; k0+=16) {
    float4 va = *(const float4*)(A + (size_t)(rowBase+lr)*Kd + k0 + lk);
    As[lk+0][lr]=va.x; As[lk+1][lr]=va.y; As[lk+2][lr]=va.z; As[lk+3][lr]=va.w;
    float4 vb = *(const float4*)(A + (size_t)(colBase+lr)*Kd + k0 + lk);
    Bs[lk+0][lr]=vb.x; Bs[lk+1][lr]=vb.y; Bs[lk+2][lr]=vb.z; Bs[lk+3][lr]=vb.w;
    __syncthreads();
    #pragma unroll
    for (int kk=0;kk<16;kk++){
      float4 a  = *(const float4*)&As[kk][ty*4];
      float4 b0 = *(const float4*)&Bs[kk][tx*4];
      float av[4]={a.x,a.y,a.z,a.w};
      float b0v[4]={b0.x,b0.y,b0.z,b0.w};
      #pragma unroll
      for (int i=0;i<4;i++)
        #pragma unroll
        for (int j=0;j<4;j++) acc[i][j] = fmaf(av[i], b0v[j], acc[i][j]);
    }
    __syncthreads();
  }
  #pragma unroll
  for (int i=0;i<4;i++){
    int r = rowBase + ty*4 + i;
    #pragma unroll
    for (int j=0;j<4;j++)
      o0[(size_t)r*M + colBase + tx*4 + j] = acc[i][j];
  }
  if (bxi != byi){
    #pragma unroll
    for (int j=0;j<4;j++){
      int c = colBase + tx*4 + j;
      #pragma unroll
      for (int i=0;i<4;i++)
        o0[(size_t)c*M + rowBase + ty*4 + i] = acc[i][j];
    }
  }
}

// ---- guarded GEMM body for 512-thread co-launch ----
template<bool DUAL, bool BN>
__device__ __forceinline__ void gemm_body_g(
    const float* __restrict__ A, const float* __restrict__ B,
    float* __restrict__ out0, float* __restrict__ out1,
    int M, int N, int Kd, int lda, int ldb, int ldo, int boff,
    const float* __restrict__ part, float invR,
    int bxi, int byi, char* smem)
{
  int rowBase = byi*64, colBase = bxi*64;
  float (*As)[64]  = (float(*)[64])smem;
  float (*Bs0)[64] = (float(*)[64])(smem + 4096);
  float (*Bs1)[64] = (float(*)[64])(smem + 8192);
  float* mu_s = (float*)(smem + 12288);
  float* var_s = mu_s + 512;
  int tid = threadIdx.x;
  bool act = tid < 256;
  if (BN){
    for (int oo=tid; oo<Kd; oo+=blockDim.x){
      float s=0, q=0;
      #pragma unroll 4
      for (int c=0;c<NCHUNK;c++){
        s += part[(size_t)c*1024 + oo];
        q += part[(size_t)(NCHUNK+c)*1024 + oo];
      }
      float mu = s*invR;
      mu_s[oo] = mu;
      var_s[oo] = q*invR - mu*mu;
    }
    __syncthreads();
  }
  int ty = tid>>4, tx = tid&15;
  float acc0[4][4] = {}, acc1[4][4] = {};
  int lr = tid>>2, lk = (tid&3)*4;
  for (int k0=0; k0<Kd; k0+=16) {
    if (act){
      float4 va = make_float4(0,0,0,0);
      int r = rowBase + lr;
      if (r < M) va = *(const float4*)(A + (size_t)r*lda + k0 + lk);
      if (BN){
        int c = k0 + lk;
        va.x = gelu_f((va.x - mu_s[c+0]) / sqrtf(var_s[c+0] + 1e-5f));
        va.y = gelu_f((va.y - mu_s[c+1]) / sqrtf(var_s[c+1] + 1e-5f));
        va.z = gelu_f((va.z - mu_s[c+2]) / sqrtf(var_s[c+2] + 1e-5f));
        va.w = gelu_f((va.w - mu_s[c+3]) / sqrtf(var_s[c+3] + 1e-5f));
      }
      As[lk+0][lr]=va.x; As[lk+1][lr]=va.y; As[lk+2][lr]=va.z; As[lk+3][lr]=va.w;
      float4 vb = make_float4(0,0,0,0), vb2 = make_float4(0,0,0,0);
      int c2 = colBase + lr;
      if (c2 < N) {
        vb = *(const float4*)(B + (size_t)c2*ldb + k0 + lk);
        if (DUAL) vb2 = *(const float4*)(B + (size_t)c2*ldb + boff + k0 + lk);
      }
      Bs0[lk+0][lr]=vb.x; Bs0[lk+1][lr]=vb.y; Bs0[lk+2][lr]=vb.z; Bs0[lk+3][lr]=vb.w;
      if (DUAL) {
        Bs1[lk+0][lr]=vb2.x-vb.x; Bs1[lk+1][lr]=vb2.y-vb.y;
        Bs1[lk+2][lr]=vb2.z-vb.z; Bs1[lk+3][lr]=vb2.w-vb.w;
      }
    }
    __syncthreads();
    if (act){
      #pragma unroll
      for (int kk=0;kk<16;kk++){
        float4 a  = *(const float4*)&As[kk][ty*4];
        float4 b0 = *(const float4*)&Bs0[kk][tx*4];
        float av[4]={a.x,a.y,a.z,a.w};
        float b0v[4]={b0.x,b0.y,b0.z,b0.w};
        #pragma unroll
        for (int i=0;i<4;i++)
          #pragma unroll
          for (int j=0;j<4;j++) acc0[i][j] = fmaf(av[i], b0v[j], acc0[i][j]);
        if (DUAL) {
          float4 b1 = *(const float4*)&Bs1[kk][tx*4];
          float b1v[4]={b1.x,b1.y,b1.z,b1.w};
          #pragma unroll
          for (int i=0;i<4;i++)
            #pragma unroll
            for (int j=0;j<4;j++) acc1[i][j] = fmaf(av[i], b1v[j], acc1[i][j]);
        }
      }
    }
    __syncthreads();
  }
  if (act){
    #pragma unroll
    for (int i=0;i<4;i++){
      int r = rowBase + ty*4 + i;
      if (r < M) {
        #pragma unroll
        for (int j=0;j<4;j++){
          int c = colBase + tx*4 + j;
          if (c < N) {
            out0[(size_t)r*ldo + c] = acc0[i][j];
            if (DUAL) out1[(size_t)r*ldo + c] = acc1[i][j];
          }
        }
      }
    }
  }
}

// ---- plain gather + max ----
__device__ __forceinline__ void gather_elem(
    const float* __restrict__ P, const int* __restrict__ nbr,
    const float* __restrict__ addA, const float* __restrict__ addB,
    float* __restrict__ out, int n_out, int n_src, int O, int K, int total, int e)
{
  if (e >= total) return;
  int o = e % O; int r = e / O;
  int b = r / n_out; int i = r % n_out;
  const int* nb = nbr + ((size_t)b*n_out + i)*K;
  float mx = -1e38f;
  for (int k=0;k<K;k++){
    int j = nb[k];
    float v = P[((size_t)b*n_src + j)*O + o];
    mx = fmaxf(mx, v);
  }
  float res = mx;
  if (addA) res += addA[e];
  if (addB) res = addB[e] + res;
  out[e] = res;
}

// ---- downsample gather with BN+gelu on load + row-norm emit ----
__device__ __forceinline__ void gatherbn_body(
    const float* __restrict__ P, const int* __restrict__ nbr,
    const float* __restrict__ part, float invR,
    float* __restrict__ out, float* __restrict__ aa,
    int n_out, int n_src, int O, int K, int blk, char* smem)
{
  float* mu_s = (float*)smem; float* var_s = mu_s + 256; float* sv = var_s + 256;
  int tid = threadIdx.x;
  for (int oo=tid; oo<O; oo+=256){
    float s=0, q=0;
    #pragma unroll 4
    for (int c=0;c<NCHUNK;c++){
      s += part[(size_t)c*1024 + oo];
      q += part[(size_t)(NCHUNK+c)*1024 + oo];
    }
    float mu = s*invR;
    mu_s[oo] = mu;
    var_s[oo] = q*invR - mu*mu;
  }
  __syncthreads();
  int e = blk*256 + tid;
  int o = e % O; int r = e / O;
  int b = r / n_out; int i = r % n_out;
  const int* nb = nbr + ((size_t)b*n_out + i)*K;
  float mu = mu_s[o], sd = sqrtf(var_s[o] + 1e-5f);
  float mx = -1e38f;
  for (int k=0;k<K;k++){
    int j = nb[k];
    float p = P[((size_t)b*n_src + j)*O + o];
    float v = gelu_f((p - mu)/sd);
    mx = fmaxf(mx, v);
  }
  out[e] = mx;
  sv[tid] = mx*mx;
  __syncthreads();
  for (int st=O>>1; st>0; st>>=1){
    if (o < st) sv[tid] += sv[tid+st];
    __syncthreads();
  }
  if (o == 0) aa[r] = sv[tid];
}

// ================= global kernels =================

#define FPS_SMEM 65664   // 16*8*512 (float4 lp) + 2*8*8 (wred)

// mega1: [fps0 seg (0-3) | knn16 (4..2051) | mlp (2052..4099)] @512thr
__global__ __launch_bounds__(512,2) void mega1(
    const float* __restrict__ xyz, const float* __restrict__ x,
    const float* __restrict__ mlpw, const float* __restrict__ mlpb,
    int* __restrict__ sind0, float* __restrict__ gdmin,
    int* __restrict__ nbr0, float* __restrict__ hA, int M0, int M1)
{
  __shared__ __align__(16) char SMEM[FPS_SMEM];
  int bid = blockIdx.x;
  if (bid < 4){
    fps_mw_seg<8,512,1024>(xyz, 4096, sind0, gdmin, bid, M0, M1, SMEM);
  } else if (bid < 4+2048){
    int kb = bid - 4;
    knn_body<16,512>(xyz, 4096, xyz, nullptr, 4096, nbr0, nullptr, kb>>9, kb&511, 0, SMEM);
  } else {
    int e = (bid - 2052)*512 + threadIdx.x;
    if (e < 4*4096*64){
      int o = e & 63; int r = e >> 6;
      int b = r / 4096; int i = r % 4096;
      const float* xb = x + (size_t)b*3*4096;
      hA[e] = ((mlpw[o*3+0]*xb[i] + mlpw[o*3+1]*xb[4096+i]) + mlpw[o*3+2]*xb[2*4096+i]) + mlpb[o];
    }
  }
}

// [fps0 seg | bngelu-from-part] @512
__global__ __launch_bounds__(512,2) void fps_bngelu(
    const float* fcur, int* sind, float* gdmin, int M0, int M1,
    float* __restrict__ xx, const float* __restrict__ part, float invR, int O, int total)
{
  __shared__ __align__(16) char SMEM[FPS_SMEM];
  if (blockIdx.x < 4){
    fps_mw_seg<8,512,1024>(fcur, 4096, sind, gdmin, blockIdx.x, M0, M1, SMEM);
    return;
  }
  float* mu_s = (float*)SMEM; float* var_s = mu_s + 512;
  for (int oo=threadIdx.x; oo<O; oo+=512){
    float s=0, q=0;
    #pragma unroll 4
    for (int c=0;c<NCHUNK;c++){
      s += part[(size_t)c*1024 + oo];
      q += part[(size_t)(NCHUNK+c)*1024 + oo];
    }
    float mu = s*invR;
    mu_s[oo] = mu;
    var_s[oo] = q*invR - mu*mu;
  }
  __syncthreads();
  int e = (blockIdx.x-4)*512 + threadIdx.x;
  if (e >= total) return;
  int o = e % O;
  float v = (xx[e]-mu_s[o]) / sqrtf(var_s[o] + 1e-5f);
  xx[e] = gelu_f(v);
}

// [fps0 seg | knn8 slice | gemm] @512
template<bool DUAL, bool BN>
__global__ __launch_bounds__(512,2) void fps0_gemm_knn(
    const float* fcur, int* sind, float* gdmin, int M0, int M1,
    const float* cand, int n, const float* qsrc, const int* qidx, int m,
    int* nbrOut, float* outc, int qoff, int NQB, int KNB,
    const float* A, const float* B, float* out0, float* out1,
    int Mg, int Ng, int Kd, int lda, int ldb, int ldo, int boff,
    const float* part, float invR, int nbx)
{
  __shared__ __align__(16) char SMEM[FPS_SMEM];
  if (blockIdx.x < 4){
    fps_mw_seg<8,512,1024>(fcur, 4096, sind, gdmin, blockIdx.x, M0, M1, SMEM);
    return;
  }
  int l = blockIdx.x - 4;
  if (l < KNB){
    knn_body<8,512>(cand, n, qsrc, qidx, m, nbrOut, outc, l/NQB, l%NQB, qoff, SMEM);
    return;
  }
  l -= KNB;
  gemm_body_g<DUAL,BN>(A,B,out0,out1,Mg,Ng,Kd,lda,ldb,ldo,boff,part,invR, l%nbx, l/nbx, SMEM);
}

// [fps0 seg | knn8 slice | gather] @512
__global__ __launch_bounds__(512,2) void fps0_gather_knn(
    const float* fcur, int* sind, float* gdmin, int M0, int M1,
    const float* cand, int n, const float* qsrc, const int* qidx, int m,
    int* nbrOut, float* outc, int qoff, int NQB, int KNB,
    const float* P, const int* nbr, const float* addA, const float* addB,
    float* out, int n_out, int n_src, int O, int K, int total)
{
  __shared__ __align__(16) char SMEM[FPS_SMEM];
  if (blockIdx.x < 4){
    fps_mw_seg<8,512,1024>(fcur, 4096, sind, gdmin, blockIdx.x, M0, M1, SMEM);
    return;
  }
  int l = blockIdx.x - 4;
  if (l < KNB){
    knn_body<8,512>(cand, n, qsrc, qidx, m, nbrOut, outc, l/NQB, l%NQB, qoff, SMEM);
    return;
  }
  int e = (l-KNB)*512 + threadIdx.x;
  gather_elem(P, nbr, addA, addB, out, n_out, n_src, O, K, total, e);
}

// [fps0 seg | knn8 slice | stats_part] @512
__global__ __launch_bounds__(512,2) void fps0_stats_knn(
    const float* fcur, int* sind, float* gdmin, int M0, int M1,
    const float* cand, int n, const float* qsrc, const int* qidx, int m,
    int* nbrOut, float* outc, int qoff, int NQB, int KNB,
    const float* __restrict__ x, int R, int O, float* __restrict__ part)
{
  __shared__ __align__(16) char SMEM[FPS_SMEM];
  if (blockIdx.x < 4){
    fps_mw_seg<8,512,1024>(fcur, 4096, sind, gdmin, blockIdx.x, M0, M1, SMEM);
    return;
  }
  int l = blockIdx.x - 4;
  if (l < KNB){
    knn_body<8,512>(cand, n, qsrc, qidx, m, nbrOut, outc, l/NQB, l%NQB, qoff, SMEM);
    return;
  }
  int o = threadIdx.x;
  if (o >= O) return;
  int chunk = l - KNB;
  int per = (R + NCHUNK - 1)/NCHUNK;
  int r0 = chunk*per, r1 = min(r0+per, R);
  float s=0, q=0;
  for (int r=r0; r<r1; r++){ float v = x[(size_t)r*O + o]; s+=v; q+=v*v; }
  part[(size_t)chunk*1024 + o] = s;
  part[(size_t)(NCHUNK+chunk)*1024 + o] = q;
}

// [knn8 tail q784-1023 (240 blk) | gatherbn SAFE blocks (784: blk%256<196)] @256
__global__ __launch_bounds__(256) void knn_gatherbn_tail(
    const float* cand, int n, const float* qsrc, const int* qidx, int m,
    int* nbrOut, float* outc, int qoff, int NQB, int KNB,
    const float* P, const int* nbr, const float* part, float invR,
    float* out, float* aa, int n_out, int n_src, int O, int K)
{
  __shared__ __align__(16) char SMEM[16384];
  if (blockIdx.x < KNB){
    int l = blockIdx.x;
    knn_body<8,256>(cand, n, qsrc, qidx, m, nbrOut, outc, l/NQB, l%NQB, qoff, SMEM);
    return;
  }
  int l = blockIdx.x - KNB;           // [0,784)
  int blk = (l/196)*256 + (l%196);    // batch-correct safe-row block
  gatherbn_body(P, nbr, part, invR, out, aa, n_out, n_src, O, K, blk, SMEM);
}

// [fps1 seg0 (multi-wave 4x64) | gatherbn UNSAFE blocks (240: blk%256>=196)] @256
__global__ __launch_bounds__(256) void fps1_gatherbn(
    const float* fcur, int* sind, float* gdmin, int M0, int M1,
    const float* P, const int* nbr, const float* part, float invR,
    float* out, float* aa, int n_out, int n_src, int O, int K)
{
  __shared__ __align__(16) char SMEM[16896];
  if (blockIdx.x < 4){
    fps_mw_seg<4,256,256>(fcur, 1024, sind, gdmin, blockIdx.x, M0, M1, SMEM);
    return;
  }
  int l = blockIdx.x - 4;             // [0,240)
  int blk = (l/60)*256 + 196 + (l%60);
  gatherbn_body(P, nbr, part, invR, out, aa, n_out, n_src, O, K, blk, SMEM);
}

// [fps1 seg (multi-wave) | symmetric Gram] @256
__global__ __launch_bounds__(256) void fps1_gram(
    const float* fcur, int* sind, float* gdmin, int M0, int M1,
    const float* Ag, float* outg, int Mg, int Kg, long sAg, long sOg, int TPB)
{
  __shared__ __align__(16) char SMEM[16896];
  if (blockIdx.x < 4){
    fps_mw_seg<4,256,256>(fcur, 1024, sind, gdmin, blockIdx.x, M0, M1, SMEM);
    return;
  }
  int l = blockIdx.x - 4;
  int bz = l / TPB, t = l % TPB;
  int bx = (int)((sqrtf(8.0f*(float)t + 1.0f) - 1.0f)*0.5f);
  while ((bx+1)*(bx+2)/2 <= t) bx++;
  while (bx*(bx+1)/2 > t) bx--;
  int by = t - bx*(bx+1)/2;
  gram_sym_body(Ag + (size_t)bz*sAg, outg + (size_t)bz*sOg, Mg, Kg, bx, by, SMEM);
}

// [fps1 seg (multi-wave) | topk] @256
__global__ __launch_bounds__(256) void fps1_topk(
    const float* fcur, int* sind, float* gdmin, int M0, int M1,
    const float* G, const float* aa, int m, int* nbr)
{
  __shared__ __align__(16) char SMEM[16896];
  if (blockIdx.x < 4){
    fps_mw_seg<4,256,256>(fcur, 1024, sind, gdmin, blockIdx.x, M0, M1, SMEM);
    return;
  }
  int l = blockIdx.x - 4;
  int qpb = m/4;
  topk_body<8>(G, aa, m, nbr, l/qpb, l%qpb, SMEM);
}

// combo: [fps_sw | gather] @256
template<int NP, int M>
__global__ __launch_bounds__(256) void fps_gather(
    const float* fcur, int fn, int* sind,
    const float* P, const int* nbr, const float* addA, const float* addB,
    float* out, int n_out, int n_src, int O, int K, int total)
{
  __shared__ __align__(16) char SMEM[(NP*64*16 > 4096) ? NP*64*16 : 4096];
  if (blockIdx.x < 4){
    if (threadIdx.x < 64) fps_sw_body<NP,M>(fcur, fn, sind, blockIdx.x, SMEM);
    return;
  }
  gather_elem(P, nbr, addA, addB, out, n_out, n_src, O, K, total, (blockIdx.x-4)*256 + threadIdx.x);
}

// combo: [knn8 | gemm] @256, template DUAL/BN
template<bool DUAL, bool BN>
__global__ __launch_bounds__(256) void knn_gemm2(
    const float* cand, int n, const float* qsrc, const int* qidx, int m,
    int* nbrOut, float* outc, int KNB,
    const float* A, const float* B, float* out0, float* out1,
    int Mg, int Ng, int Kd, int boff,
    const float* part, float invR, int nbx)
{
  __shared__ __align__(16) char SMEM[16896];
  if (blockIdx.x < KNB){
    int qpb = m/4;
    knn_body<8,256>(cand, n, qsrc, qidx, m, nbrOut, outc, blockIdx.x/qpb, blockIdx.x%qpb, 0, SMEM);
    return;
  }
  int l = blockIdx.x - KNB;
  gemm_body<DUAL,BN>(A,B,out0,out1,Mg,Ng,Kd,Kd,DUAL?2*Kd:Kd,Ng,boff,0,0,0,part,invR, l%nbx, l/nbx, 0, SMEM);
}

// combo: [knn8 | gatherbn] @256
__global__ __launch_bounds__(256) void knn_gatherbn(
    const float* cand, int n, const float* qsrc, const int* qidx, int m,
    int* nbrOut, int KNB,
    const float* P, const int* nbr, const float* part, float invR,
    float* out, float* aa, int n_out, int n_src, int O, int K)
{
  __shared__ __align__(16) char SMEM[16384];
  if (blockIdx.x < KNB){
    int qpb = m/4;
    knn_body<8,256>(cand, n, qsrc, qidx, m, nbrOut, nullptr, blockIdx.x/qpb, blockIdx.x%qpb, 0, SMEM);
    return;
  }
  gatherbn_body(P, nbr, part, invR, out, aa, n_out, n_src, O, K, blockIdx.x-KNB, SMEM);
}

// combo: [Gram | gemm1 (DUAL)] @256
__global__ __launch_bounds__(256) void gram_gemm(
    const float* Ag, float* outg, int Mg, int Kg, long sAg, long sOg,
    int ngx, int ngy, int NG,
    const float* A2, const float* B2, float* o20, float* o21,
    int M2, int N2, int K2, int boff2, int nb2x)
{
  __shared__ __align__(16) char SMEM[16896];
  int l = blockIdx.x;
  if (l < NG){
    int bx = l % ngx, by = (l/ngx) % ngy, bz = l/(ngx*ngy);
    gemm_body<false,false>(Ag,Ag,outg,nullptr,Mg,Mg,Kg,Kg,Kg,Mg,0,sAg,sAg,sOg,nullptr,0.f,bx,by,bz,SMEM);
    return;
  }
  l -= NG;
  gemm_body<true,false>(A2,B2,o20,o21,M2,N2,K2,K2,2*K2,N2,boff2,0,0,0,nullptr,0.f, l%nb2x, l/nb2x, 0, SMEM);
}

// fused gemm2(BN) + shortcut-gemm
__global__ __launch_bounds__(256) void gemm2sc(
    const float* A2, const float* B2, float* o20, float* o21, int R, int O2, int O1v,
    const float* part, float invR,
    const float* Asc, const float* Bsc, float* osc, int Cin,
    int nbx, int nby)
{
  __shared__ __align__(16) char SMEM[16896];
  int l = blockIdx.x;
  int half = nbx*nby;
  if (l < half){
    gemm_body<true,true>(A2,B2,o20,o21,R,O2,O1v,O1v,2*O1v,O2,O1v,0,0,0,part,invR, l%nbx, l/nbx, 0, SMEM);
  } else {
    l -= half;
    gemm_body<false,false>(Asc,Bsc,osc,nullptr,R,O2,Cin,Cin,Cin,O2,0,0,0,0,nullptr,0.f, l%nbx, l/nbx, 0, SMEM);
  }
}

__global__ __launch_bounds__(256) void gathermax_kernel(
    const float* P, const int* nbr, const float* addA, const float* addB,
    float* out, int n_out, int n_src, int O, int K, int total)
{
  gather_elem(P, nbr, addA, addB, out, n_out, n_src, O, K, total, blockIdx.x*256 + threadIdx.x);
}

__global__ __launch_bounds__(256) void gatherbn_kernel(
    const float* P, const int* nbr, const float* part, float invR,
    float* out, float* aa, int n_out, int n_src, int O, int K)
{
  __shared__ __align__(16) char SMEM[3072];
  gatherbn_body(P, nbr, part, invR, out, aa, n_out, n_src, O, K, blockIdx.x, SMEM);
}

// standalone top-K
template<int K>
__global__ __launch_bounds__(256) void topk_wave(
    const float* __restrict__ G, const float* __restrict__ aa, int m,
    int* __restrict__ nbr)
{
  __shared__ __align__(16) char SMEM[4096];
  topk_body<K>(G, aa, m, nbr, blockIdx.y, blockIdx.x, SMEM);
}

__global__ void stats_part_kernel(const float* __restrict__ x, int R, int O,
                                  float* __restrict__ part)
{
  int o = threadIdx.x;
  int chunk = blockIdx.x;
  int per = (R + NCHUNK - 1)/NCHUNK;
  int r0 = chunk*per, r1 = min(r0+per, R);
  float s=0, q=0;
  for (int r=r0; r<r1; r++){ float v = x[(size_t)r*O + o]; s+=v; q+=v*v; }
  part[(size_t)chunk*1024 + o] = s;
  part[(size_t)(NCHUNK+chunk)*1024 + o] = q;
}

// head with BN+gelu folded on load
__global__ __launch_bounds__(1024) void head_kernel(const float* __restrict__ h,
    const float* __restrict__ part, float invR,
    const float* __restrict__ w1, const float* __restrict__ w2,
    const float* __restrict__ b2, float* __restrict__ out)
{
  __shared__ __align__(16) float mu_s[512], var_s[512];
  __shared__ __align__(16) float g[4*512];
  __shared__ __align__(16) float t[4*256];
  int tid = threadIdx.x;
  for (int oo=tid; oo<512; oo+=1024){
    float s=0, q=0;
    #pragma unroll 4
    for (int c=0;c<NCHUNK;c++){
      s += part[(size_t)c*1024 + oo];
      q += part[(size_t)(NCHUNK+c)*1024 + oo];
    }
    float mu = s*invR;
    mu_s[oo] = mu;
    var_s[oo] = q*invR - mu*mu;
  }
  __syncthreads();
  for (int e=tid; e<2048; e+=1024){
    int b=e>>9, c=e&511;
    float mu = mu_s[c], sd = sqrtf(var_s[c] + 1e-5f);
    float s=0;
    for (int p=0;p<16;p++){
      float v = h[((size_t)(b*16+p))*512 + c];
      s += gelu_f((v-mu)/sd);
    }
    g[e] = s * (1.0f/16.0f);
  }
  __syncthreads();
  {
    int b = tid>>8, j = tid&255;
    const float4* gr = (const float4*)(g + b*512);
    const float4* wr = (const float4*)(w1 + (size_t)j*512);
    float s=0;
    for (int c=0;c<128;c++){
      float4 a=gr[c], w=wr[c];
      s = fmaf(a.x,w.x, fmaf(a.y,w.y, fmaf(a.z,w.z, fmaf(a.w,w.w, s))));
    }
    t[tid] = s;
  }
  __syncthreads();
  if (tid < 256){
    float v0=t[tid], v1=t[256+tid], v2=t[512+tid], v3=t[768+tid];
    float mu = ((v0+v1)+v2+v3)*0.25f;
    float d0=v0-mu, d1=v1-mu, d2=v2-mu, d3=v3-mu;
    float var = ((d0*d0+d1*d1)+d2*d2+d3*d3)*0.25f;
    float sq = sqrtf(var + 1e-5f);
    t[tid]     = gelu_f(d0/sq);
    t[256+tid] = gelu_f(d1/sq);
    t[512+tid] = gelu_f(d2/sq);
    t[768+tid] = gelu_f(d3/sq);
  }
  __syncthreads();
  if (tid < 160){
    int b = tid/40, o = tid%40;
    const float* tr = t + b*256; const float* wr = w2 + (size_t)o*256;
    float s=0;
    for (int j=0;j<256;j++) s = fmaf(tr[j], wr[j], s);
    out[tid] = s + b2[o];
  }
}

// =====================================================================
extern "C" void kernel_launch(void* const* d_in, const int* in_sizes, int n_in,
                              void* d_out, int out_size, void* d_ws, size_t ws_size,
                              hipStream_t stream)
{
  const float* x    = (const float*)d_in[0];
  const float* xyz  = (const float*)d_in[1];
  const float* mlpw = (const float*)d_in[2];
  const float* mlpb = (const float*)d_in[3];
  const float* c0l1 = (const float*)d_in[4];
  const float* c0l2 = (const float*)d_in[5];
  const float* L1[4] = {(const float*)d_in[6], (const float*)d_in[8],
                        (const float*)d_in[11], (const float*)d_in[14]};
  const float* L2[4] = {(const float*)d_in[7], (const float*)d_in[9],
                        (const float*)d_in[12], (const float*)d_in[15]};
  const float* SC[4] = {nullptr, (const float*)d_in[10],
                        (const float*)d_in[13], (const float*)d_in[16]};
  const float* hw1 = (const float*)d_in[17];
  const float* hw2 = (const float*)d_in[18];
  const float* hb2 = (const float*)d_in[19];
  float* out = (float*)d_out;

  float* ws = (float*)d_ws;
  const size_t MF = 1024*1024;
  float* D    = ws;               // 4M floats (Gram)
  float* hA   = ws + 4*MF;
  float* hX   = ws + 5*MF;
  float* hP   = ws + 6*MF;
  float* hCT  = ws + 7*MF;
  float* hSH  = ws + 8*MF;
  float* hH1  = ws + 9*MF;
  float* hOUT = ws + 10*MF;
  float* aux  = ws + 11*MF;
  int*   nbr0  = (int*)aux;                 aux += 262144;
  int*   nbrS0 = (int*)aux;                 aux += 32768;
  int*   nbrS1 = (int*)aux;                 aux += 8192;
  int*   nbrS2 = (int*)aux;                 aux += 2048;
  int*   nbrS3 = (int*)aux;                 aux += 512;
  int*   nbrF  = (int*)aux;                 aux += 32768;
  int*   sind0 = (int*)aux;                 aux += 4096;
  int*   sind1 = (int*)aux;                 aux += 1024;
  int*   sind2 = (int*)aux;                 aux += 256;
  int*   sind3 = (int*)aux;                 aux += 64;
  float* aa    = aux;                       aux += 4096;
  float* cur1  = aux;                       aux += 12288;
  float* cur2  = aux;                       aux += 3072;
  float* cur3  = aux;                       aux += 768;
  float* part  = aux;                       aux += 65536;
  float* gdmin = aux;                       aux += 16384;

  int tot0 = 4*4096*64;

  // ---- fps0 windows with ec0 chain + query-sliced knn8 riding along (R19 budgets) ----
  // W1: fps 0-300 | knn16 | mlp
  mega1<<<4100, 512, 0, stream>>>(xyz, x, mlpw, mlpb, sind0, gdmin, nbr0, hA, 0, 300);
  stats_part_kernel<<<NCHUNK, 64, 0, stream>>>(hA, 16384, 64, part);
  // W2: fps 300-345 | bngelu(hA)
  fps_bngelu<<<4+2048, 512, 0, stream>>>(xyz, sind0, gdmin, 300, 345, hA, part, 1.0f/16384.0f, 64, tot0);
  // W3: fps 345-470 | knn8 q0-255 | ec0 gemm1
  fps0_gemm_knn<true,false><<<4+128+256, 512, 0, stream>>>(xyz, sind0, gdmin, 345, 470,
      xyz, 4096, xyz, sind0, 1024, nbrS0, cur1, 0, 32, 128,
      hA, c0l1, hP, hCT, 16384, 64, 64, 64, 128, 64, 64, nullptr, 0.f, 1);
  // W4: fps 470-645 | knn8 q256-463 | ec0 gather1
  fps0_gather_knn<<<4+104+2048, 512, 0, stream>>>(xyz, sind0, gdmin, 470, 645,
      xyz, 4096, xyz, sind0, 1024, nbrS0, cur1, 256, 26, 104,
      hP, nbr0, hCT, nullptr, hH1, 4096, 4096, 64, 16, 1048576);
  stats_part_kernel<<<NCHUNK, 64, 0, stream>>>(hH1, 16384, 64, part);
  // W5: fps 645-720 | knn8 q464-639 | ec0 gemm2 (BN)
  fps0_gemm_knn<true,true><<<4+88+256, 512, 0, stream>>>(xyz, sind0, gdmin, 645, 720,
      xyz, 4096, xyz, sind0, 1024, nbrS0, cur1, 464, 22, 88,
      hH1, c0l2, hP, hCT, 16384, 64, 64, 64, 128, 64, 64, part, 1.0f/16384.0f, 1);
  // W6: fps 720-820 | knn8 q640-687 | ec0 gather2 (+hA residual)
  fps0_gather_knn<<<4+24+2048, 512, 0, stream>>>(xyz, sind0, gdmin, 720, 820,
      xyz, 4096, xyz, sind0, 1024, nbrS0, cur1, 640, 6, 24,
      hP, nbr0, hCT, hA, hOUT, 4096, 4096, 64, 16, 1048576);
  // W7: fps 820-1024 | knn8 q688-783 | stats(hOUT)
  fps0_stats_knn<<<4+48+NCHUNK, 512, 0, stream>>>(xyz, sind0, gdmin, 820, 1024,
      xyz, 4096, xyz, sind0, 1024, nbrS0, cur1, 688, 12, 48,
      hOUT, 16384, 64, part);
  // fps0 complete; hOUT = ec0 output (raw) + stats in part

  // ---- stage0 pre ----
  // Tail: [knn8 q784-1023 (240 blk) | gatherbn SAFE rows (784 blk, i<784 per batch)]
  knn_gatherbn_tail<<<240+784, 256, 0, stream>>>(
      xyz, 4096, xyz, sind0, 1024, nbrS0, cur1, 784, 60, 240,
      hOUT, nbrS0, part, 1.0f/16384.0f, hX, aa, 1024, 4096, 64, 8);
  // [fps1 seg0 0-86 (multi-wave) | gatherbn UNSAFE rows (240 blk, i>=784)]
  fps1_gatherbn<<<4+240, 256, 0, stream>>>(cur1, sind1, gdmin, 0, 86,
      hOUT, nbrS0, part, 1.0f/16384.0f, hX, aa, 1024, 4096, 64, 8);
  // [fps1 seg1 86-171 (multi-wave) | Gram0 symmetric: 136 tiles x 4 batches]
  fps1_gram<<<4+544, 256, 0, stream>>>(cur1, sind1, gdmin, 86, 171,
      hX, D, 1024, 64, (long)1024*64, (long)1024*1024, 136);
  // [fps1 seg2 171-256 (multi-wave) | topk m=1024]
  fps1_topk<<<4+1024, 256, 0, stream>>>(cur1, sind1, gdmin, 171, 256,
      D, aa, 1024, nbrF);
  // [knn8_1 (m=256 vs cur1; needs full sind1) | s0 gemm1]
  knn_gemm2<true,false><<<256+64,256,0,stream>>>(cur1, 1024, cur1, sind1, 256,
      nbrS1, cur2, 256,
      hX, L1[0], hP, hCT, 4096, 64, 64, 64, nullptr, 0.f, 1);
  // [fps2 (cur2, 256->64) | s0 gather1]
  fps_gather<4,64><<<4+1024,256,0,stream>>>(cur2, 256, sind2,
      hP, nbrF, hCT, nullptr, hH1, 1024, 1024, 64, 8, 262144);
  stats_part_kernel<<<NCHUNK, 64, 0, stream>>>(hH1, 4096, 64, part);
  // [knn8_2 (m=64 vs cur2) | s0 gemm2 BN]
  knn_gemm2<true,true><<<64+64,256,0,stream>>>(cur2, 256, cur2, sind2, 64,
      nbrS2, cur3, 64,
      hH1, L2[0], hP, hCT, 4096, 64, 64, 64, part, 1.0f/4096.0f, 1);
  // [fps3 (cur3, 64->16) | s0 gather2 (+hX residual)]
  fps_gather<1,16><<<4+1024,256,0,stream>>>(cur3, 64, sind3,
      hP, nbrF, hCT, hX, hA, 1024, 1024, 64, 8, 262144);
  stats_part_kernel<<<NCHUNK, 64, 0, stream>>>(hA, 4096, 64, part);
  // [knn8_3 (m=16 vs cur3) | stage1 gatherbn hA->hX + aa]
  knn_gatherbn<<<16+256,256,0,stream>>>(cur3, 64, cur3, sind3, 16,
      nbrS3, 16,
      hA, nbrS1, part, 1.0f/4096.0f, hX, aa, 256, 1024, 64, 8);
  // hX = stage1 downsampled input (post-BN), aa = norms

  // ---- stages 1-3 (geometry precomputed) ----
  const int   mArr[3]   = {256, 64, 16};
  const int   nsrcArr[3]= {1024, 256, 64};
  const int   CinArr[3] = {64, 128, 256};
  const int   OArr[3]   = {128, 256, 512};
  const int*  nbrSs[3]  = {nbrS1, nbrS2, nbrS3};
  float* hcur = hA;
  float invRprev = 1.0f/4096.0f;
  for (int s=0;s<3;s++){
    int m = mArr[s], nsrc = nsrcArr[s], Cin = CinArr[s], O1 = OArr[s], O2 = OArr[s];
    int R = 4*m;
    int th = R*Cin;
    if (s > 0){
      gatherbn_kernel<<<th/256,256,0,stream>>>(hcur, nbrSs[s], part, invRprev,
                                               hX, aa, m, nsrc, Cin, 8);
    }
    int ngx = (m+63)/64, ngy = (m+63)/64;
    int NG = ngx*ngy*4;
    int nb1x = (O1+63)/64, nb1y = (R+63)/64;
    gram_gemm<<<NG + nb1x*nb1y, 256, 0, stream>>>(
        hX, D, m, Cin, (long)m*Cin, (long)m*m, ngx, ngy, NG,
        hX, L1[s+1], hP, hCT, R, O1, Cin, Cin, nb1x);
    topk_wave<8><<<dim3(m/4,4),256,0,stream>>>(D, aa, m, nbrF);
    int t1 = R*O1;
    gathermax_kernel<<<(t1+255)/256,256,0,stream>>>(hP, nbrF, hCT, nullptr, hH1, m, m, O1, 8, t1);
    stats_part_kernel<<<NCHUNK, O1, 0, stream>>>(hH1, R, O1, part);
    int nbx = (O2+63)/64, nby = (R+63)/64;
    gemm2sc<<<2*nbx*nby,256,0,stream>>>(hH1, L2[s+1], hP, hCT, R, O2, O1, part, 1.0f/R,
                                        hX, SC[s+1], hSH, Cin, nbx, nby);
    int t2 = R*O2;
    float* outbuf = (s&1) ? hA : hOUT;
    gathermax_kernel<<<(t2+255)/256,256,0,stream>>>(hP, nbrF, hCT, hSH, outbuf, m, m, O2, 8, t2);
    stats_part_kernel<<<NCHUNK, O2, 0, stream>>>(outbuf, R, O2, part);
    hcur = outbuf;
    invRprev = 1.0f/R;
  }

  head_kernel<<<1,1024,0,stream>>>(hcur, part, 1.0f/64.0f, hw1, hw2, hb2, out);
}